// Round 10
// baseline (209.021 us; speedup 1.0000x reference)
//
#include <hip/hip_runtime.h>

constexpr int HID  = 128;
constexpr int DEGS = 16;   // deg counter stride (ints): 1 counter per 64B line

typedef __attribute__((ext_vector_type(8))) short bf16x8;
typedef __attribute__((ext_vector_type(4))) float f32x4;

__device__ __forceinline__ unsigned short f2bf(float f) {
    unsigned int u = __float_as_uint(f);
    u += 0x7fffu + ((u >> 16) & 1u);            // RNE
    return (unsigned short)(u >> 16);
}
__device__ __forceinline__ float bf_lo(unsigned int v) { return __uint_as_float(v << 16); }
__device__ __forceinline__ float bf_hi(unsigned int v) { return __uint_as_float(v & 0xffff0000u); }

__device__ __forceinline__ void gload16(const void* g, void* l) {
    __builtin_amdgcn_global_load_lds(
        (const __attribute__((address_space(1))) void*)g,
        (__attribute__((address_space(3))) void*)l, 16, 0, 0);
}

// ===========================================================================
// prep_k: fused [hist_rank | cvt_w | cvt_x]; deg padded to 1 counter/line.
// ===========================================================================
struct PrepArgs {
    const int* dst; int* deg; int* rank; int nEdges;          // hist_rank
    const float* ws[6]; unsigned short* wd[6];                // cvt_w
    const float* x; unsigned short* xb; int n4;               // cvt_x
    int histBlocks, cvtwBlocks;                               // partition
};

__global__ __launch_bounds__(256) void prep_k(PrepArgs a)
{
    const int b   = blockIdx.x;
    const int tid = threadIdx.x;
    if (b < a.histBlocks) {
        const int i = b * 256 + tid;
        if (i < a.nEdges) a.rank[i] = atomicAdd(&a.deg[(size_t)a.dst[i] * DEGS], 1);
    } else if (b < a.histBlocks + a.cvtwBlocks) {
        const int idx   = b - a.histBlocks;
        const int which = idx >> 4;                 // 6 weights x 16 blocks
        const int i     = (idx & 15) * 256 + tid;   // < 4096
        const float4 v = reinterpret_cast<const float4*>(a.ws[which])[i];
        ushort4 o;
        o.x = f2bf(v.x); o.y = f2bf(v.y); o.z = f2bf(v.z); o.w = f2bf(v.w);
        reinterpret_cast<ushort4*>(a.wd[which])[i] = o;
    } else {
        const int i = (b - a.histBlocks - a.cvtwBlocks) * 256 + tid;
        if (i >= a.n4) return;
        const float4 v = reinterpret_cast<const float4*>(a.x)[i];
        ushort4 o;
        o.x = f2bf(v.x); o.y = f2bf(v.y); o.z = f2bf(v.z); o.w = f2bf(v.w);
        reinterpret_cast<ushort4*>(a.xb)[i] = o;
    }
}

// ===========================================================================
// CSR scan chain (deg reads strided by DEGS)
// ===========================================================================
__global__ __launch_bounds__(256) void scan1_k(
    const int* __restrict__ deg, int* __restrict__ part,
    int* __restrict__ blockSums, int n)
{
    __shared__ int s[256];
    const int t = threadIdx.x;
    const int i = blockIdx.x * 1024 + t * 4;
    const int e0 = (i + 0 < n) ? deg[(size_t)(i + 0) * DEGS] : 0;
    const int e1 = (i + 1 < n) ? deg[(size_t)(i + 1) * DEGS] : 0;
    const int e2 = (i + 2 < n) ? deg[(size_t)(i + 2) * DEGS] : 0;
    const int e3 = (i + 3 < n) ? deg[(size_t)(i + 3) * DEGS] : 0;
    const int local = e0 + e1 + e2 + e3;
    s[t] = local;
    __syncthreads();
    for (int off = 1; off < 256; off <<= 1) {
        int v = 0;
        if (t >= off) v = s[t - off];
        __syncthreads();
        if (t >= off) s[t] += v;
        __syncthreads();
    }
    const int incl = s[t];
    int excl = incl - local;
    if (t == 255) blockSums[blockIdx.x] = incl;
    if (i + 0 < n) part[i + 0] = excl; excl += e0;
    if (i + 1 < n) part[i + 1] = excl; excl += e1;
    if (i + 2 < n) part[i + 2] = excl; excl += e2;
    if (i + 3 < n) part[i + 3] = excl;
}

__global__ __launch_bounds__(128) void scan2_k(int* __restrict__ blockSums, int nb)
{
    __shared__ int s[128];
    const int t = threadIdx.x;
    const int v = (t < nb) ? blockSums[t] : 0;
    s[t] = v;
    __syncthreads();
    for (int off = 1; off < 128; off <<= 1) {
        int u = 0;
        if (t >= off) u = s[t - off];
        __syncthreads();
        if (t >= off) s[t] += u;
        __syncthreads();
    }
    if (t < nb) blockSums[t] = s[t] - v;   // exclusive
}

__global__ __launch_bounds__(256) void scan3_k(
    const int* __restrict__ part, const int* __restrict__ blockSums,
    int* __restrict__ rowStart, int n, int nEdges)
{
    const int i = blockIdx.x * blockDim.x + threadIdx.x;
    if (i < n) rowStart[i] = part[i] + blockSums[i >> 10];
    if (i == n) rowStart[n] = nEdges;
}

__global__ __launch_bounds__(256) void fill2_k(
    const int* __restrict__ src, const int* __restrict__ dst,
    const int* __restrict__ rank, const int* __restrict__ rowStart,
    int* __restrict__ eSrc, int nEdges)
{
    const int i = blockIdx.x * blockDim.x + threadIdx.x;
    if (i < nEdges) eSrc[rowStart[dst[i]] + rank[i]] = src[i];
}

// ===========================================================================
// Gather aggregation (bf16): 4 nodes per wave, 16 lanes per node,
// uint4 (8 bf16) per lane; batched ILP 8/4/2/1. (proven R7 config)
// ===========================================================================
__global__ __launch_bounds__(256) void gather_agg_k(
    const unsigned short* __restrict__ feat,
    const int*            __restrict__ rowStart,
    const int*            __restrict__ eSrc,
    unsigned short*       __restrict__ agg,
    int nNodes)
{
    const int wid  = (blockIdx.x * blockDim.x + threadIdx.x) >> 6;
    const int lane = threadIdx.x & 63;
    const int g    = lane >> 4;        // subgroup 0..3
    const int sl   = lane & 15;        // lane within subgroup
    const int node = wid * 4 + g;
    if (node >= nNodes) return;

    const int beg = rowStart[node];
    const int end = rowStart[node + 1];
    const size_t colOff = (size_t)sl * 8;      // elements (16B)
    const int gbase = g << 4;

    float acc[8];
#pragma unroll
    for (int q = 0; q < 8; ++q) acc[q] = 0.f;

    for (int base = beg; base < end; base += 16) {
        const int cnt = min(16, end - base);
        const int si = eSrc[base + min(sl, cnt - 1)];   // 16 indices per subgroup

        int j = 0;
        for (; j + 8 <= cnt; j += 8) {
            uint4 v[8];
#pragma unroll
            for (int q = 0; q < 8; ++q) {
                const int s = __shfl(si, gbase + j + q, 64);
                v[q] = *reinterpret_cast<const uint4*>(feat + (size_t)s * HID + colOff);
            }
#pragma unroll
            for (int q = 0; q < 8; ++q) {
                acc[0] += bf_lo(v[q].x); acc[1] += bf_hi(v[q].x);
                acc[2] += bf_lo(v[q].y); acc[3] += bf_hi(v[q].y);
                acc[4] += bf_lo(v[q].z); acc[5] += bf_hi(v[q].z);
                acc[6] += bf_lo(v[q].w); acc[7] += bf_hi(v[q].w);
            }
        }
        if (j + 4 <= cnt) {
            uint4 v[4];
#pragma unroll
            for (int q = 0; q < 4; ++q) {
                const int s = __shfl(si, gbase + j + q, 64);
                v[q] = *reinterpret_cast<const uint4*>(feat + (size_t)s * HID + colOff);
            }
#pragma unroll
            for (int q = 0; q < 4; ++q) {
                acc[0] += bf_lo(v[q].x); acc[1] += bf_hi(v[q].x);
                acc[2] += bf_lo(v[q].y); acc[3] += bf_hi(v[q].y);
                acc[4] += bf_lo(v[q].z); acc[5] += bf_hi(v[q].z);
                acc[6] += bf_lo(v[q].w); acc[7] += bf_hi(v[q].w);
            }
            j += 4;
        }
        if (j + 2 <= cnt) {
            uint4 v[2];
#pragma unroll
            for (int q = 0; q < 2; ++q) {
                const int s = __shfl(si, gbase + j + q, 64);
                v[q] = *reinterpret_cast<const uint4*>(feat + (size_t)s * HID + colOff);
            }
#pragma unroll
            for (int q = 0; q < 2; ++q) {
                acc[0] += bf_lo(v[q].x); acc[1] += bf_hi(v[q].x);
                acc[2] += bf_lo(v[q].y); acc[3] += bf_hi(v[q].y);
                acc[4] += bf_lo(v[q].z); acc[5] += bf_hi(v[q].z);
                acc[6] += bf_lo(v[q].w); acc[7] += bf_hi(v[q].w);
            }
            j += 2;
        }
        if (j < cnt) {
            const int s = __shfl(si, gbase + j, 64);
            const uint4 v = *reinterpret_cast<const uint4*>(feat + (size_t)s * HID + colOff);
            acc[0] += bf_lo(v.x); acc[1] += bf_hi(v.x);
            acc[2] += bf_lo(v.y); acc[3] += bf_hi(v.y);
            acc[4] += bf_lo(v.z); acc[5] += bf_hi(v.z);
            acc[6] += bf_lo(v.w); acc[7] += bf_hi(v.w);
        }
    }

    uint4 o;
    o.x = (unsigned int)f2bf(acc[0]) | ((unsigned int)f2bf(acc[1]) << 16);
    o.y = (unsigned int)f2bf(acc[2]) | ((unsigned int)f2bf(acc[3]) << 16);
    o.z = (unsigned int)f2bf(acc[4]) | ((unsigned int)f2bf(acc[5]) << 16);
    o.w = (unsigned int)f2bf(acc[6]) | ((unsigned int)f2bf(acc[7]) << 16);
    *reinterpret_cast<uint4*>(agg + (size_t)node * HID + colOff) = o;
}

// ===========================================================================
// bf16 MFMA dual-GEMM, single-buffered 32KB LDS (proven round-3 structure;
// 4 blocks/CU -> grid fits in ONE occupancy round, no tail quantization).
// ===========================================================================
template <int MODE>
__global__ __launch_bounds__(256) void gemm_mfma_k(
    const unsigned short* __restrict__ X,
    const unsigned short* __restrict__ AGG,
    const unsigned short* __restrict__ Wroot,
    const unsigned short* __restrict__ Wrel,
    const float*          __restrict__ bias,
    void*                 __restrict__ OUTv,
    int nRows)
{
    __shared__ unsigned short Xs[128 * 64];
    __shared__ unsigned short Ws[128 * 64];

    const int tid  = threadIdx.x;
    const int lane = tid & 63;
    const int w    = tid >> 6;
    const int row0 = blockIdx.x * 128;

    const int wr = w >> 1, wc = w & 1;
    const int R0 = wr * 64, C0 = wc * 64;
    const int lr = lane & 15, lk = lane >> 4;
    const int swz = (lr & 7) << 4;           // read-side XOR (bytes)

    const int rsub    = lane >> 3;                              // 0..7
    const int srcColB = (((lane & 7) ^ rsub) << 4);             // pre-swizzled src col
    const int stHalf  = w & 1;
    const int rowMax  = nRows - 1;

    f32x4 acc[4][4];
#pragma unroll
    for (int m = 0; m < 4; ++m)
#pragma unroll
        for (int n = 0; n < 4; ++n) acc[m][n] = f32x4{0.f, 0.f, 0.f, 0.f};

#pragma unroll
    for (int half = 0; half < 2; ++half) {
        const unsigned short* F  = half ? AGG  : X;
        const unsigned short* Wm = half ? Wrel : Wroot;
#pragma unroll
        for (int c = 0; c < 2; ++c) {
            const int k0 = c * 64;
            if (w < 2) {
#pragma unroll
                for (int q = 0; q < 8; ++q) {
                    const int row = stHalf * 64 + q * 8 + rsub;
                    const int gr  = min(row0 + row, rowMax);
                    gload16((const char*)(F + (size_t)gr * HID + k0) + srcColB,
                            Xs + (stHalf * 64 + q * 8) * 64);
                }
            } else {
#pragma unroll
                for (int q = 0; q < 8; ++q) {
                    const int row = stHalf * 64 + q * 8 + rsub;
                    gload16((const char*)(Wm + (size_t)row * HID + k0) + srcColB,
                            Ws + (stHalf * 64 + q * 8) * 64);
                }
            }
            __syncthreads();

#pragma unroll
            for (int ks = 0; ks < 2; ++ks) {
                bf16x8 af[4], bfr[4];
                const int kB = (ks * 64 + lk * 16) ^ swz;
#pragma unroll
                for (int m = 0; m < 4; ++m) {
                    const int row = R0 + m * 16 + lr;
                    af[m] = *reinterpret_cast<const bf16x8*>((const char*)Xs + row * 128 + kB);
                }
#pragma unroll
                for (int n = 0; n < 4; ++n) {
                    const int col = C0 + n * 16 + lr;
                    bfr[n] = *reinterpret_cast<const bf16x8*>((const char*)Ws + col * 128 + kB);
                }
#pragma unroll
                for (int m = 0; m < 4; ++m)
#pragma unroll
                    for (int n = 0; n < 4; ++n)
                        acc[m][n] = __builtin_amdgcn_mfma_f32_16x16x32_bf16(
                            af[m], bfr[n], acc[m][n], 0, 0, 0);
            }
            __syncthreads();
        }
    }

    float bv[4];
#pragma unroll
    for (int n = 0; n < 4; ++n) bv[n] = bias[C0 + n * 16 + lr];

#pragma unroll
    for (int m = 0; m < 4; ++m) {
        const int rbase = row0 + R0 + m * 16 + lk * 4;
#pragma unroll
        for (int j = 0; j < 4; ++j) {
            const int r = rbase + j;
            if (r < nRows) {
#pragma unroll
                for (int n = 0; n < 4; ++n) {
                    const int col = C0 + n * 16 + lr;
                    float v = acc[m][n][j] + bv[n];
                    if (MODE == 0) {
                        v = fmaxf(v, 0.f);
                        ((unsigned short*)OUTv)[(size_t)r * HID + col] = f2bf(v);
                    } else {
                        ((float*)OUTv)[(size_t)r * HID + col] = v;
                    }
                }
            }
        }
    }
}

// ===========================================================================
extern "C" void kernel_launch(void* const* d_in, const int* in_sizes, int n_in,
                              void* d_out, int out_size, void* d_ws, size_t ws_size,
                              hipStream_t stream)
{
    const float* x      = (const float*)d_in[0];
    const int*   ei     = (const int*)  d_in[1];
    const float* Wrel0  = (const float*)d_in[2];
    const float* b0     = (const float*)d_in[3];
    const float* Wroot0 = (const float*)d_in[4];
    const float* Wrel1  = (const float*)d_in[5];
    const float* b1     = (const float*)d_in[6];
    const float* Wroot1 = (const float*)d_in[7];
    const float* Wrel2  = (const float*)d_in[8];
    const float* b2     = (const float*)d_in[9];
    const float* Wroot2 = (const float*)d_in[10];

    const int nNodes = in_sizes[0] / HID;   // 100000
    const int nEdges = in_sizes[1] / 2;     // 640000
    const int* srcI = ei;
    const int* dstI = ei + nEdges;
    const size_t nF = (size_t)nNodes * HID;

    float* OUT = (float*)d_out;

    // ---- workspace layout (ws_size ~268MB, measured via harness poison)
    unsigned short* xb   = (unsigned short*)d_ws;
    unsigned short* hA   = xb + nF;
    unsigned short* hB   = hA + nF;
    unsigned short* aggb = hB + nF;
    unsigned short* wb   = aggb + nF;          // 6 x 128*128 bf16
    int* deg       = (int*)(wb + 6 * HID * HID);   // nNodes*DEGS (6.4MB padded)
    int* part      = deg + (size_t)nNodes * DEGS;
    int* rowStart  = part + nNodes;            // nNodes+1
    int* blockSums = rowStart + nNodes + 1;    // <=128
    int* rank      = blockSums + 128;          // nEdges
    int* eSrc      = rank + nEdges;            // nEdges

    unsigned short* Wrel0b  = wb + 0 * HID * HID;
    unsigned short* Wroot0b = wb + 1 * HID * HID;
    unsigned short* Wrel1b  = wb + 2 * HID * HID;
    unsigned short* Wroot1b = wb + 3 * HID * HID;
    unsigned short* Wrel2b  = wb + 4 * HID * HID;
    unsigned short* Wroot2b = wb + 5 * HID * HID;

    // ---- fused prep: hist_rank (first) | cvt_w | cvt_x
    hipMemsetAsync(deg, 0, (size_t)nNodes * DEGS * sizeof(int), stream);
    PrepArgs pa;
    pa.dst = dstI; pa.deg = deg; pa.rank = rank; pa.nEdges = nEdges;
    pa.ws[0] = Wrel0;  pa.wd[0] = Wrel0b;
    pa.ws[1] = Wroot0; pa.wd[1] = Wroot0b;
    pa.ws[2] = Wrel1;  pa.wd[2] = Wrel1b;
    pa.ws[3] = Wroot1; pa.wd[3] = Wroot1b;
    pa.ws[4] = Wrel2;  pa.wd[4] = Wrel2b;
    pa.ws[5] = Wroot2; pa.wd[5] = Wroot2b;
    pa.x = x; pa.xb = xb; pa.n4 = (int)(nF / 4);
    pa.histBlocks = (nEdges + 255) / 256;                   // 2500
    pa.cvtwBlocks = 96;
    const int prepGrid = pa.histBlocks + pa.cvtwBlocks + (pa.n4 + 255) / 256;
    prep_k<<<prepGrid, 256, 0, stream>>>(pa);

    // ---- CSR scan chain + fill
    const int nb = (nNodes + 1023) / 1024;
    scan1_k<<<nb, 256, 0, stream>>>(deg, part, blockSums, nNodes);
    scan2_k<<<1, 128, 0, stream>>>(blockSums, nb);
    scan3_k<<<(nNodes + 256) / 256, 256, 0, stream>>>(part, blockSums, rowStart, nNodes, nEdges);
    fill2_k<<<(nEdges + 255) / 256, 256, 0, stream>>>(srcI, dstI, rank, rowStart, eSrc, nEdges);

    const int aGrid = (int)(((size_t)(nNodes + 3) / 4 * 64 + 255) / 256);  // 4 nodes/wave
    const int gGrid = (nNodes + 127) / 128;

    // ---- layer 0
    gather_agg_k<<<aGrid, 256, 0, stream>>>(xb, rowStart, eSrc, aggb, nNodes);
    gemm_mfma_k<0><<<gGrid, 256, 0, stream>>>(xb, aggb, Wroot0b, Wrel0b, b0, hA, nNodes);

    // ---- layer 1
    gather_agg_k<<<aGrid, 256, 0, stream>>>(hA, rowStart, eSrc, aggb, nNodes);
    gemm_mfma_k<0><<<gGrid, 256, 0, stream>>>(hA, aggb, Wroot1b, Wrel1b, b1, hB, nNodes);

    // ---- layer 2 (f32 out, no ReLU)
    gather_agg_k<<<aGrid, 256, 0, stream>>>(hB, rowStart, eSrc, aggb, nNodes);
    gemm_mfma_k<1><<<gGrid, 256, 0, stream>>>(hB, aggb, Wroot2b, Wrel2b, b2, OUT, nNodes);
}

// Round 11
// 202.989 us; speedup vs baseline: 1.0297x; 1.0297x over previous
//
#include <hip/hip_runtime.h>

constexpr int HID = 128;

typedef __attribute__((ext_vector_type(8))) short bf16x8;
typedef __attribute__((ext_vector_type(4))) float f32x4;

__device__ __forceinline__ unsigned short f2bf(float f) {
    unsigned int u = __float_as_uint(f);
    u += 0x7fffu + ((u >> 16) & 1u);            // RNE
    return (unsigned short)(u >> 16);
}
__device__ __forceinline__ float bf_lo(unsigned int v) { return __uint_as_float(v << 16); }
__device__ __forceinline__ float bf_hi(unsigned int v) { return __uint_as_float(v & 0xffff0000u); }

__device__ __forceinline__ void gload16(const void* g, void* l) {
    __builtin_amdgcn_global_load_lds(
        (const __attribute__((address_space(1))) void*)g,
        (__attribute__((address_space(3))) void*)l, 16, 0, 0);
}

// ===========================================================================
// prep_k: fused [hist_rank (8-edge ILP) | cvt_w | cvt_x].
// Hist: each thread handles 8 edges -> 8 atomics-with-return IN FLIGHT
// (vs 1 before). If the 40us hist pass was latency-bound, this cuts it ~3x;
// if fabric-throughput-bound it's null (discriminating experiment).
// ===========================================================================
struct PrepArgs {
    const int* dst; int* deg; int* rank; int nEdges;          // hist_rank
    const float* ws[6]; unsigned short* wd[6];                // cvt_w
    const float* x; unsigned short* xb; int n4;               // cvt_x
    int histBlocks, cvtwBlocks;                               // partition
};

__global__ __launch_bounds__(256) void prep_k(PrepArgs a)
{
    const int b   = blockIdx.x;
    const int tid = threadIdx.x;
    if (b < a.histBlocks) {
        const int i0 = (b * 256 + tid) * 8;
        if (i0 + 8 <= a.nEdges) {
            const int4 d0 = *reinterpret_cast<const int4*>(a.dst + i0);
            const int4 d1 = *reinterpret_cast<const int4*>(a.dst + i0 + 4);
            int4 r0, r1;
            r0.x = atomicAdd(&a.deg[d0.x], 1);
            r0.y = atomicAdd(&a.deg[d0.y], 1);
            r0.z = atomicAdd(&a.deg[d0.z], 1);
            r0.w = atomicAdd(&a.deg[d0.w], 1);
            r1.x = atomicAdd(&a.deg[d1.x], 1);
            r1.y = atomicAdd(&a.deg[d1.y], 1);
            r1.z = atomicAdd(&a.deg[d1.z], 1);
            r1.w = atomicAdd(&a.deg[d1.w], 1);
            *reinterpret_cast<int4*>(a.rank + i0)     = r0;
            *reinterpret_cast<int4*>(a.rank + i0 + 4) = r1;
        } else {
            for (int i = i0; i < a.nEdges; ++i)
                a.rank[i] = atomicAdd(&a.deg[a.dst[i]], 1);
        }
    } else if (b < a.histBlocks + a.cvtwBlocks) {
        const int idx   = b - a.histBlocks;
        const int which = idx >> 4;                 // 6 weights x 16 blocks
        const int i     = (idx & 15) * 256 + tid;   // < 4096
        const float4 v = reinterpret_cast<const float4*>(a.ws[which])[i];
        ushort4 o;
        o.x = f2bf(v.x); o.y = f2bf(v.y); o.z = f2bf(v.z); o.w = f2bf(v.w);
        reinterpret_cast<ushort4*>(a.wd[which])[i] = o;
    } else {
        const int i = (b - a.histBlocks - a.cvtwBlocks) * 256 + tid;
        if (i >= a.n4) return;
        const float4 v = reinterpret_cast<const float4*>(a.x)[i];
        ushort4 o;
        o.x = f2bf(v.x); o.y = f2bf(v.y); o.z = f2bf(v.z); o.w = f2bf(v.w);
        reinterpret_cast<ushort4*>(a.xb)[i] = o;
    }
}

// ===========================================================================
// CSR scan chain
// ===========================================================================
__global__ __launch_bounds__(256) void scan1_k(
    const int* __restrict__ deg, int* __restrict__ part,
    int* __restrict__ blockSums, int n)
{
    __shared__ int s[256];
    const int t = threadIdx.x;
    const int i = blockIdx.x * 1024 + t * 4;
    const int e0 = (i + 0 < n) ? deg[i + 0] : 0;
    const int e1 = (i + 1 < n) ? deg[i + 1] : 0;
    const int e2 = (i + 2 < n) ? deg[i + 2] : 0;
    const int e3 = (i + 3 < n) ? deg[i + 3] : 0;
    const int local = e0 + e1 + e2 + e3;
    s[t] = local;
    __syncthreads();
    for (int off = 1; off < 256; off <<= 1) {
        int v = 0;
        if (t >= off) v = s[t - off];
        __syncthreads();
        if (t >= off) s[t] += v;
        __syncthreads();
    }
    const int incl = s[t];
    int excl = incl - local;
    if (t == 255) blockSums[blockIdx.x] = incl;
    if (i + 0 < n) part[i + 0] = excl; excl += e0;
    if (i + 1 < n) part[i + 1] = excl; excl += e1;
    if (i + 2 < n) part[i + 2] = excl; excl += e2;
    if (i + 3 < n) part[i + 3] = excl;
}

__global__ __launch_bounds__(128) void scan2_k(int* __restrict__ blockSums, int nb)
{
    __shared__ int s[128];
    const int t = threadIdx.x;
    const int v = (t < nb) ? blockSums[t] : 0;
    s[t] = v;
    __syncthreads();
    for (int off = 1; off < 128; off <<= 1) {
        int u = 0;
        if (t >= off) u = s[t - off];
        __syncthreads();
        if (t >= off) s[t] += u;
        __syncthreads();
    }
    if (t < nb) blockSums[t] = s[t] - v;   // exclusive
}

__global__ __launch_bounds__(256) void scan3_k(
    const int* __restrict__ part, const int* __restrict__ blockSums,
    int* __restrict__ rowStart, int n, int nEdges)
{
    const int i = blockIdx.x * blockDim.x + threadIdx.x;
    if (i < n) rowStart[i] = part[i] + blockSums[i >> 10];
    if (i == n) rowStart[n] = nEdges;
}

__global__ __launch_bounds__(256) void fill2_k(
    const int* __restrict__ src, const int* __restrict__ dst,
    const int* __restrict__ rank, const int* __restrict__ rowStart,
    int* __restrict__ eSrc, int nEdges)
{
    const int i = blockIdx.x * blockDim.x + threadIdx.x;
    if (i < nEdges) eSrc[rowStart[dst[i]] + rank[i]] = src[i];
}

// ===========================================================================
// Gather aggregation (bf16): 4 nodes per wave, 16 lanes per node,
// uint4 (8 bf16) per lane; batched ILP 8/4/2/1. (proven R7/R9 config)
// ===========================================================================
__global__ __launch_bounds__(256) void gather_agg_k(
    const unsigned short* __restrict__ feat,
    const int*            __restrict__ rowStart,
    const int*            __restrict__ eSrc,
    unsigned short*       __restrict__ agg,
    int nNodes)
{
    const int wid  = (blockIdx.x * blockDim.x + threadIdx.x) >> 6;
    const int lane = threadIdx.x & 63;
    const int g    = lane >> 4;        // subgroup 0..3
    const int sl   = lane & 15;        // lane within subgroup
    const int node = wid * 4 + g;
    if (node >= nNodes) return;

    const int beg = rowStart[node];
    const int end = rowStart[node + 1];
    const size_t colOff = (size_t)sl * 8;      // elements (16B)
    const int gbase = g << 4;

    float acc[8];
#pragma unroll
    for (int q = 0; q < 8; ++q) acc[q] = 0.f;

    for (int base = beg; base < end; base += 16) {
        const int cnt = min(16, end - base);
        const int si = eSrc[base + min(sl, cnt - 1)];   // 16 indices per subgroup

        int j = 0;
        for (; j + 8 <= cnt; j += 8) {
            uint4 v[8];
#pragma unroll
            for (int q = 0; q < 8; ++q) {
                const int s = __shfl(si, gbase + j + q, 64);
                v[q] = *reinterpret_cast<const uint4*>(feat + (size_t)s * HID + colOff);
            }
#pragma unroll
            for (int q = 0; q < 8; ++q) {
                acc[0] += bf_lo(v[q].x); acc[1] += bf_hi(v[q].x);
                acc[2] += bf_lo(v[q].y); acc[3] += bf_hi(v[q].y);
                acc[4] += bf_lo(v[q].z); acc[5] += bf_hi(v[q].z);
                acc[6] += bf_lo(v[q].w); acc[7] += bf_hi(v[q].w);
            }
        }
        if (j + 4 <= cnt) {
            uint4 v[4];
#pragma unroll
            for (int q = 0; q < 4; ++q) {
                const int s = __shfl(si, gbase + j + q, 64);
                v[q] = *reinterpret_cast<const uint4*>(feat + (size_t)s * HID + colOff);
            }
#pragma unroll
            for (int q = 0; q < 4; ++q) {
                acc[0] += bf_lo(v[q].x); acc[1] += bf_hi(v[q].x);
                acc[2] += bf_lo(v[q].y); acc[3] += bf_hi(v[q].y);
                acc[4] += bf_lo(v[q].z); acc[5] += bf_hi(v[q].z);
                acc[6] += bf_lo(v[q].w); acc[7] += bf_hi(v[q].w);
            }
            j += 4;
        }
        if (j + 2 <= cnt) {
            uint4 v[2];
#pragma unroll
            for (int q = 0; q < 2; ++q) {
                const int s = __shfl(si, gbase + j + q, 64);
                v[q] = *reinterpret_cast<const uint4*>(feat + (size_t)s * HID + colOff);
            }
#pragma unroll
            for (int q = 0; q < 2; ++q) {
                acc[0] += bf_lo(v[q].x); acc[1] += bf_hi(v[q].x);
                acc[2] += bf_lo(v[q].y); acc[3] += bf_hi(v[q].y);
                acc[4] += bf_lo(v[q].z); acc[5] += bf_hi(v[q].z);
                acc[6] += bf_lo(v[q].w); acc[7] += bf_hi(v[q].w);
            }
            j += 2;
        }
        if (j < cnt) {
            const int s = __shfl(si, gbase + j, 64);
            const uint4 v = *reinterpret_cast<const uint4*>(feat + (size_t)s * HID + colOff);
            acc[0] += bf_lo(v.x); acc[1] += bf_hi(v.x);
            acc[2] += bf_lo(v.y); acc[3] += bf_hi(v.y);
            acc[4] += bf_lo(v.z); acc[5] += bf_hi(v.z);
            acc[6] += bf_lo(v.w); acc[7] += bf_hi(v.w);
        }
    }

    uint4 o;
    o.x = (unsigned int)f2bf(acc[0]) | ((unsigned int)f2bf(acc[1]) << 16);
    o.y = (unsigned int)f2bf(acc[2]) | ((unsigned int)f2bf(acc[3]) << 16);
    o.z = (unsigned int)f2bf(acc[4]) | ((unsigned int)f2bf(acc[5]) << 16);
    o.w = (unsigned int)f2bf(acc[6]) | ((unsigned int)f2bf(acc[7]) << 16);
    *reinterpret_cast<uint4*>(agg + (size_t)node * HID + colOff) = o;
}

// ===========================================================================
// bf16 MFMA dual-GEMM, 2-phase double-buffered pipeline (proven R9 config).
// ===========================================================================
__device__ __forceinline__ void stage_tile(
    const unsigned short* __restrict__ F, const unsigned short* __restrict__ Wm,
    unsigned short* XsBuf, unsigned short* WsBuf,
    int w, int stHalf, int rsub, int srcColB, int k0, int row0, int rowMax)
{
    if (w < 2) {
#pragma unroll
        for (int q = 0; q < 8; ++q) {
            const int row = stHalf * 64 + q * 8 + rsub;
            const int gr  = min(row0 + row, rowMax);
            gload16((const char*)(F + (size_t)gr * HID + k0) + srcColB,
                    XsBuf + (stHalf * 64 + q * 8) * 64);
        }
    } else {
#pragma unroll
        for (int q = 0; q < 8; ++q) {
            const int row = stHalf * 64 + q * 8 + rsub;
            gload16((const char*)(Wm + (size_t)row * HID + k0) + srcColB,
                    WsBuf + (stHalf * 64 + q * 8) * 64);
        }
    }
}

template <int MODE>
__global__ __launch_bounds__(256) void gemm_mfma_k(
    const unsigned short* __restrict__ X,
    const unsigned short* __restrict__ AGG,
    const unsigned short* __restrict__ Wroot,
    const unsigned short* __restrict__ Wrel,
    const float*          __restrict__ bias,
    void*                 __restrict__ OUTv,
    int nRows)
{
    __shared__ unsigned short Xs[2][128 * 64];
    __shared__ unsigned short Ws[2][128 * 64];

    const int tid  = threadIdx.x;
    const int lane = tid & 63;
    const int w    = tid >> 6;
    const int row0 = blockIdx.x * 128;

    const int wr = w >> 1, wc = w & 1;
    const int R0 = wr * 64, C0 = wc * 64;
    const int lr = lane & 15, lk = lane >> 4;
    const int swz = (lr & 7) << 4;

    const int rsub    = lane >> 3;
    const int srcColB = (((lane & 7) ^ rsub) << 4);
    const int stHalf  = w & 1;
    const int rowMax  = nRows - 1;

    f32x4 acc[4][4];
#pragma unroll
    for (int m = 0; m < 4; ++m)
#pragma unroll
        for (int n = 0; n < 4; ++n) acc[m][n] = f32x4{0.f, 0.f, 0.f, 0.f};

    stage_tile(X, Wroot, Xs[0], Ws[0], w, stHalf, rsub, srcColB, 0, row0, rowMax);

#pragma unroll
    for (int t = 0; t < 4; ++t) {
        const int cur = t & 1;
        if (t < 3) {
            const unsigned short* Fn = (t + 1 < 2) ? X : AGG;
            const unsigned short* Wn = (t + 1 < 2) ? Wroot : Wrel;
            stage_tile(Fn, Wn, Xs[cur ^ 1], Ws[cur ^ 1],
                       w, stHalf, rsub, srcColB, ((t + 1) & 1) * 64, row0, rowMax);
            asm volatile("s_waitcnt vmcnt(8)" ::: "memory");
        } else {
            asm volatile("s_waitcnt vmcnt(0)" ::: "memory");
        }
        __builtin_amdgcn_s_barrier();

#pragma unroll
        for (int ks = 0; ks < 2; ++ks) {
            bf16x8 af[4], bfr[4];
            const int kB = (ks * 64 + lk * 16) ^ swz;
#pragma unroll
            for (int m = 0; m < 4; ++m) {
                const int row = R0 + m * 16 + lr;
                af[m] = *reinterpret_cast<const bf16x8*>((const char*)Xs[cur] + row * 128 + kB);
            }
#pragma unroll
            for (int n = 0; n < 4; ++n) {
                const int col = C0 + n * 16 + lr;
                bfr[n] = *reinterpret_cast<const bf16x8*>((const char*)Ws[cur] + col * 128 + kB);
            }
#pragma unroll
            for (int m = 0; m < 4; ++m)
#pragma unroll
                for (int n = 0; n < 4; ++n)
                    acc[m][n] = __builtin_amdgcn_mfma_f32_16x16x32_bf16(
                        af[m], bfr[n], acc[m][n], 0, 0, 0);
        }
        if (t < 3) __builtin_amdgcn_s_barrier();
    }

    float bv[4];
#pragma unroll
    for (int n = 0; n < 4; ++n) bv[n] = bias[C0 + n * 16 + lr];

#pragma unroll
    for (int m = 0; m < 4; ++m) {
        const int rbase = row0 + R0 + m * 16 + lk * 4;
#pragma unroll
        for (int j = 0; j < 4; ++j) {
            const int r = rbase + j;
            if (r < nRows) {
#pragma unroll
                for (int n = 0; n < 4; ++n) {
                    const int col = C0 + n * 16 + lr;
                    float v = acc[m][n][j] + bv[n];
                    if (MODE == 0) {
                        v = fmaxf(v, 0.f);
                        ((unsigned short*)OUTv)[(size_t)r * HID + col] = f2bf(v);
                    } else {
                        ((float*)OUTv)[(size_t)r * HID + col] = v;
                    }
                }
            }
        }
    }
}

// ===========================================================================
extern "C" void kernel_launch(void* const* d_in, const int* in_sizes, int n_in,
                              void* d_out, int out_size, void* d_ws, size_t ws_size,
                              hipStream_t stream)
{
    const float* x      = (const float*)d_in[0];
    const int*   ei     = (const int*)  d_in[1];
    const float* Wrel0  = (const float*)d_in[2];
    const float* b0     = (const float*)d_in[3];
    const float* Wroot0 = (const float*)d_in[4];
    const float* Wrel1  = (const float*)d_in[5];
    const float* b1     = (const float*)d_in[6];
    const float* Wroot1 = (const float*)d_in[7];
    const float* Wrel2  = (const float*)d_in[8];
    const float* b2     = (const float*)d_in[9];
    const float* Wroot2 = (const float*)d_in[10];

    const int nNodes = in_sizes[0] / HID;   // 100000
    const int nEdges = in_sizes[1] / 2;     // 640000
    const int* srcI = ei;
    const int* dstI = ei + nEdges;
    const size_t nF = (size_t)nNodes * HID;

    float* OUT = (float*)d_out;

    // ---- workspace layout
    unsigned short* xb   = (unsigned short*)d_ws;
    unsigned short* hA   = xb + nF;
    unsigned short* hB   = hA + nF;
    unsigned short* aggb = hB + nF;
    unsigned short* wb   = aggb + nF;          // 6 x 128*128 bf16
    int* deg       = (int*)(wb + 6 * HID * HID);
    int* part      = deg + nNodes;
    int* rowStart  = part + nNodes;            // nNodes+1
    int* blockSums = rowStart + nNodes + 1;    // <=128
    int* rank      = blockSums + 128;          // nEdges
    int* eSrc      = rank + nEdges;            // nEdges

    unsigned short* Wrel0b  = wb + 0 * HID * HID;
    unsigned short* Wroot0b = wb + 1 * HID * HID;
    unsigned short* Wrel1b  = wb + 2 * HID * HID;
    unsigned short* Wroot1b = wb + 3 * HID * HID;
    unsigned short* Wrel2b  = wb + 4 * HID * HID;
    unsigned short* Wroot2b = wb + 5 * HID * HID;

    // ---- fused prep: hist_rank ILP (first) | cvt_w | cvt_x
    hipMemsetAsync(deg, 0, (size_t)nNodes * sizeof(int), stream);
    PrepArgs pa;
    pa.dst = dstI; pa.deg = deg; pa.rank = rank; pa.nEdges = nEdges;
    pa.ws[0] = Wrel0;  pa.wd[0] = Wrel0b;
    pa.ws[1] = Wroot0; pa.wd[1] = Wroot0b;
    pa.ws[2] = Wrel1;  pa.wd[2] = Wrel1b;
    pa.ws[3] = Wroot1; pa.wd[3] = Wroot1b;
    pa.ws[4] = Wrel2;  pa.wd[4] = Wrel2b;
    pa.ws[5] = Wroot2; pa.wd[5] = Wroot2b;
    pa.x = x; pa.xb = xb; pa.n4 = (int)(nF / 4);
    pa.histBlocks = (nEdges + 2047) / 2048;                 // 313 (8 edges/thread)
    pa.cvtwBlocks = 96;
    const int prepGrid = pa.histBlocks + pa.cvtwBlocks + (pa.n4 + 255) / 256;
    prep_k<<<prepGrid, 256, 0, stream>>>(pa);

    // ---- CSR scan chain + fill
    const int nb = (nNodes + 1023) / 1024;
    scan1_k<<<nb, 256, 0, stream>>>(deg, part, blockSums, nNodes);
    scan2_k<<<1, 128, 0, stream>>>(blockSums, nb);
    scan3_k<<<(nNodes + 256) / 256, 256, 0, stream>>>(part, blockSums, rowStart, nNodes, nEdges);
    fill2_k<<<(nEdges + 255) / 256, 256, 0, stream>>>(srcI, dstI, rank, rowStart, eSrc, nEdges);

    const int aGrid = (int)(((size_t)(nNodes + 3) / 4 * 64 + 255) / 256);  // 4 nodes/wave
    const int gGrid = (nNodes + 127) / 128;

    // ---- layer 0
    gather_agg_k<<<aGrid, 256, 0, stream>>>(xb, rowStart, eSrc, aggb, nNodes);
    gemm_mfma_k<0><<<gGrid, 256, 0, stream>>>(xb, aggb, Wroot0b, Wrel0b, b0, hA, nNodes);

    // ---- layer 1
    gather_agg_k<<<aGrid, 256, 0, stream>>>(hA, rowStart, eSrc, aggb, nNodes);
    gemm_mfma_k<0><<<gGrid, 256, 0, stream>>>(hA, aggb, Wroot1b, Wrel1b, b1, hB, nNodes);

    // ---- layer 2 (f32 out, no ReLU)
    gather_agg_k<<<aGrid, 256, 0, stream>>>(hB, rowStart, eSrc, aggb, nNodes);
    gemm_mfma_k<1><<<gGrid, 256, 0, stream>>>(hB, aggb, Wroot2b, Wrel2b, b2, OUT, nNodes);
}

// Round 12
// 201.418 us; speedup vs baseline: 1.0377x; 1.0078x over previous
//
#include <hip/hip_runtime.h>

constexpr int HID = 128;

typedef __attribute__((ext_vector_type(8))) short bf16x8;
typedef __attribute__((ext_vector_type(4))) float f32x4;

__device__ __forceinline__ unsigned short f2bf(float f) {
    unsigned int u = __float_as_uint(f);
    u += 0x7fffu + ((u >> 16) & 1u);            // RNE
    return (unsigned short)(u >> 16);
}
__device__ __forceinline__ float bf_lo(unsigned int v) { return __uint_as_float(v << 16); }
__device__ __forceinline__ float bf_hi(unsigned int v) { return __uint_as_float(v & 0xffff0000u); }

__device__ __forceinline__ void gload16(const void* g, void* l) {
    __builtin_amdgcn_global_load_lds(
        (const __attribute__((address_space(1))) void*)g,
        (__attribute__((address_space(3))) void*)l, 16, 0, 0);
}

// ===========================================================================
// prep_k: fused [hist_rank (8-edge ILP) | cvt_w | cvt_x]  (proven R11)
// ===========================================================================
struct PrepArgs {
    const int* dst; int* deg; int* rank; int nEdges;          // hist_rank
    const float* ws[6]; unsigned short* wd[6];                // cvt_w
    const float* x; unsigned short* xb; int n4;               // cvt_x
    int histBlocks, cvtwBlocks;                               // partition
};

__global__ __launch_bounds__(256) void prep_k(PrepArgs a)
{
    const int b   = blockIdx.x;
    const int tid = threadIdx.x;
    if (b < a.histBlocks) {
        const int i0 = (b * 256 + tid) * 8;
        if (i0 + 8 <= a.nEdges) {
            const int4 d0 = *reinterpret_cast<const int4*>(a.dst + i0);
            const int4 d1 = *reinterpret_cast<const int4*>(a.dst + i0 + 4);
            int4 r0, r1;
            r0.x = atomicAdd(&a.deg[d0.x], 1);
            r0.y = atomicAdd(&a.deg[d0.y], 1);
            r0.z = atomicAdd(&a.deg[d0.z], 1);
            r0.w = atomicAdd(&a.deg[d0.w], 1);
            r1.x = atomicAdd(&a.deg[d1.x], 1);
            r1.y = atomicAdd(&a.deg[d1.y], 1);
            r1.z = atomicAdd(&a.deg[d1.z], 1);
            r1.w = atomicAdd(&a.deg[d1.w], 1);
            *reinterpret_cast<int4*>(a.rank + i0)     = r0;
            *reinterpret_cast<int4*>(a.rank + i0 + 4) = r1;
        } else {
            for (int i = i0; i < a.nEdges; ++i)
                a.rank[i] = atomicAdd(&a.deg[a.dst[i]], 1);
        }
    } else if (b < a.histBlocks + a.cvtwBlocks) {
        const int idx   = b - a.histBlocks;
        const int which = idx >> 4;                 // 6 weights x 16 blocks
        const int i     = (idx & 15) * 256 + tid;   // < 4096
        const float4 v = reinterpret_cast<const float4*>(a.ws[which])[i];
        ushort4 o;
        o.x = f2bf(v.x); o.y = f2bf(v.y); o.z = f2bf(v.z); o.w = f2bf(v.w);
        reinterpret_cast<ushort4*>(a.wd[which])[i] = o;
    } else {
        const int i = (b - a.histBlocks - a.cvtwBlocks) * 256 + tid;
        if (i >= a.n4) return;
        const float4 v = reinterpret_cast<const float4*>(a.x)[i];
        ushort4 o;
        o.x = f2bf(v.x); o.y = f2bf(v.y); o.z = f2bf(v.z); o.w = f2bf(v.w);
        reinterpret_cast<ushort4*>(a.xb)[i] = o;
    }
}

// ===========================================================================
// scan1: per-block (1024 nodes) exclusive scan -> part + blockSums
// ===========================================================================
__global__ __launch_bounds__(256) void scan1_k(
    const int* __restrict__ deg, int* __restrict__ part,
    int* __restrict__ blockSums, int n)
{
    __shared__ int s[256];
    const int t = threadIdx.x;
    const int i = blockIdx.x * 1024 + t * 4;
    const int e0 = (i + 0 < n) ? deg[i + 0] : 0;
    const int e1 = (i + 1 < n) ? deg[i + 1] : 0;
    const int e2 = (i + 2 < n) ? deg[i + 2] : 0;
    const int e3 = (i + 3 < n) ? deg[i + 3] : 0;
    const int local = e0 + e1 + e2 + e3;
    s[t] = local;
    __syncthreads();
    for (int off = 1; off < 256; off <<= 1) {
        int v = 0;
        if (t >= off) v = s[t - off];
        __syncthreads();
        if (t >= off) s[t] += v;
        __syncthreads();
    }
    const int incl = s[t];
    int excl = incl - local;
    if (t == 255) blockSums[blockIdx.x] = incl;
    if (i + 0 < n) part[i + 0] = excl; excl += e0;
    if (i + 1 < n) part[i + 1] = excl; excl += e1;
    if (i + 2 < n) part[i + 2] = excl; excl += e2;
    if (i + 3 < n) part[i + 3] = excl;
}

// ===========================================================================
// scanfill_k: fused [scan2 (redundant per-block) + scan3 | fill2].
// Every block redundantly exclusive-scans blockSums (<=128 ints, ~us-scale
// free) in LDS, eliminating the cross-kernel dependency; then node-domain
// blocks write rowStart, edge-domain blocks scatter eSrc.
// ===========================================================================
__global__ __launch_bounds__(256) void scanfill_k(
    const int* __restrict__ part, const int* __restrict__ blockSums, int nb,
    int* __restrict__ rowStart,
    const int* __restrict__ src, const int* __restrict__ dst,
    const int* __restrict__ rank, int* __restrict__ eSrc,
    int n, int nEdges, int nodeBlocks)
{
    __shared__ int bs[128];
    const int t = threadIdx.x;
    // redundant exclusive scan of blockSums in every block
    if (t < 128) {
        const int v = (t < nb) ? blockSums[t] : 0;
        bs[t] = v;
    }
    __syncthreads();
    for (int off = 1; off < 128; off <<= 1) {
        int u = 0;
        if (t >= off && t < 128) u = bs[t - off];
        __syncthreads();
        if (t >= off && t < 128) bs[t] += u;
        __syncthreads();
    }
    // bs now inclusive; convert on use: excl(k) = bs[k] - orig. Simpler:
    // store exclusive via second pass
    __shared__ int bse[128];
    if (t < 128) {
        const int v = (t < nb) ? blockSums[t] : 0;
        bse[t] = bs[t] - v;
    }
    __syncthreads();

    if (blockIdx.x < (unsigned)nodeBlocks) {
        const int i = blockIdx.x * 256 + t;
        if (i < n) rowStart[i] = part[i] + bse[i >> 10];
        if (i == n) rowStart[n] = nEdges;
    } else {
        const int i = (blockIdx.x - nodeBlocks) * 256 + t;
        if (i < nEdges) {
            const int d = dst[i];
            eSrc[part[d] + bse[d >> 10] + rank[i]] = src[i];
        }
    }
}

// ===========================================================================
// Gather aggregation (bf16): 4 nodes/wave, 16 lanes/node, uint4/lane,
// batched ILP 8/4/2/1. (proven R7/R9 config)
// ===========================================================================
__global__ __launch_bounds__(256) void gather_agg_k(
    const unsigned short* __restrict__ feat,
    const int*            __restrict__ rowStart,
    const int*            __restrict__ eSrc,
    unsigned short*       __restrict__ agg,
    int nNodes)
{
    const int wid  = (blockIdx.x * blockDim.x + threadIdx.x) >> 6;
    const int lane = threadIdx.x & 63;
    const int g    = lane >> 4;
    const int sl   = lane & 15;
    const int node = wid * 4 + g;
    if (node >= nNodes) return;

    const int beg = rowStart[node];
    const int end = rowStart[node + 1];
    const size_t colOff = (size_t)sl * 8;
    const int gbase = g << 4;

    float acc[8];
#pragma unroll
    for (int q = 0; q < 8; ++q) acc[q] = 0.f;

    for (int base = beg; base < end; base += 16) {
        const int cnt = min(16, end - base);
        const int si = eSrc[base + min(sl, cnt - 1)];

        int j = 0;
        for (; j + 8 <= cnt; j += 8) {
            uint4 v[8];
#pragma unroll
            for (int q = 0; q < 8; ++q) {
                const int s = __shfl(si, gbase + j + q, 64);
                v[q] = *reinterpret_cast<const uint4*>(feat + (size_t)s * HID + colOff);
            }
#pragma unroll
            for (int q = 0; q < 8; ++q) {
                acc[0] += bf_lo(v[q].x); acc[1] += bf_hi(v[q].x);
                acc[2] += bf_lo(v[q].y); acc[3] += bf_hi(v[q].y);
                acc[4] += bf_lo(v[q].z); acc[5] += bf_hi(v[q].z);
                acc[6] += bf_lo(v[q].w); acc[7] += bf_hi(v[q].w);
            }
        }
        if (j + 4 <= cnt) {
            uint4 v[4];
#pragma unroll
            for (int q = 0; q < 4; ++q) {
                const int s = __shfl(si, gbase + j + q, 64);
                v[q] = *reinterpret_cast<const uint4*>(feat + (size_t)s * HID + colOff);
            }
#pragma unroll
            for (int q = 0; q < 4; ++q) {
                acc[0] += bf_lo(v[q].x); acc[1] += bf_hi(v[q].x);
                acc[2] += bf_lo(v[q].y); acc[3] += bf_hi(v[q].y);
                acc[4] += bf_lo(v[q].z); acc[5] += bf_hi(v[q].z);
                acc[6] += bf_lo(v[q].w); acc[7] += bf_hi(v[q].w);
            }
            j += 4;
        }
        if (j + 2 <= cnt) {
            uint4 v[2];
#pragma unroll
            for (int q = 0; q < 2; ++q) {
                const int s = __shfl(si, gbase + j + q, 64);
                v[q] = *reinterpret_cast<const uint4*>(feat + (size_t)s * HID + colOff);
            }
#pragma unroll
            for (int q = 0; q < 2; ++q) {
                acc[0] += bf_lo(v[q].x); acc[1] += bf_hi(v[q].x);
                acc[2] += bf_lo(v[q].y); acc[3] += bf_hi(v[q].y);
                acc[4] += bf_lo(v[q].z); acc[5] += bf_hi(v[q].z);
                acc[6] += bf_lo(v[q].w); acc[7] += bf_hi(v[q].w);
            }
            j += 2;
        }
        if (j < cnt) {
            const int s = __shfl(si, gbase + j, 64);
            const uint4 v = *reinterpret_cast<const uint4*>(feat + (size_t)s * HID + colOff);
            acc[0] += bf_lo(v.x); acc[1] += bf_hi(v.x);
            acc[2] += bf_lo(v.y); acc[3] += bf_hi(v.y);
            acc[4] += bf_lo(v.z); acc[5] += bf_hi(v.z);
            acc[6] += bf_lo(v.w); acc[7] += bf_hi(v.w);
        }
    }

    uint4 o;
    o.x = (unsigned int)f2bf(acc[0]) | ((unsigned int)f2bf(acc[1]) << 16);
    o.y = (unsigned int)f2bf(acc[2]) | ((unsigned int)f2bf(acc[3]) << 16);
    o.z = (unsigned int)f2bf(acc[4]) | ((unsigned int)f2bf(acc[5]) << 16);
    o.w = (unsigned int)f2bf(acc[6]) | ((unsigned int)f2bf(acc[7]) << 16);
    *reinterpret_cast<uint4*>(agg + (size_t)node * HID + colOff) = o;
}

// ===========================================================================
// bf16 MFMA dual-GEMM, 2-phase double-buffered pipeline (proven R9 config).
// ===========================================================================
__device__ __forceinline__ void stage_tile(
    const unsigned short* __restrict__ F, const unsigned short* __restrict__ Wm,
    unsigned short* XsBuf, unsigned short* WsBuf,
    int w, int stHalf, int rsub, int srcColB, int k0, int row0, int rowMax)
{
    if (w < 2) {
#pragma unroll
        for (int q = 0; q < 8; ++q) {
            const int row = stHalf * 64 + q * 8 + rsub;
            const int gr  = min(row0 + row, rowMax);
            gload16((const char*)(F + (size_t)gr * HID + k0) + srcColB,
                    XsBuf + (stHalf * 64 + q * 8) * 64);
        }
    } else {
#pragma unroll
        for (int q = 0; q < 8; ++q) {
            const int row = stHalf * 64 + q * 8 + rsub;
            gload16((const char*)(Wm + (size_t)row * HID + k0) + srcColB,
                    WsBuf + (stHalf * 64 + q * 8) * 64);
        }
    }
}

template <int MODE>
__global__ __launch_bounds__(256) void gemm_mfma_k(
    const unsigned short* __restrict__ X,
    const unsigned short* __restrict__ AGG,
    const unsigned short* __restrict__ Wroot,
    const unsigned short* __restrict__ Wrel,
    const float*          __restrict__ bias,
    void*                 __restrict__ OUTv,
    int nRows)
{
    __shared__ unsigned short Xs[2][128 * 64];
    __shared__ unsigned short Ws[2][128 * 64];

    const int tid  = threadIdx.x;
    const int lane = tid & 63;
    const int w    = tid >> 6;
    const int row0 = blockIdx.x * 128;

    const int wr = w >> 1, wc = w & 1;
    const int R0 = wr * 64, C0 = wc * 64;
    const int lr = lane & 15, lk = lane >> 4;
    const int swz = (lr & 7) << 4;

    const int rsub    = lane >> 3;
    const int srcColB = (((lane & 7) ^ rsub) << 4);
    const int stHalf  = w & 1;
    const int rowMax  = nRows - 1;

    f32x4 acc[4][4];
#pragma unroll
    for (int m = 0; m < 4; ++m)
#pragma unroll
        for (int n = 0; n < 4; ++n) acc[m][n] = f32x4{0.f, 0.f, 0.f, 0.f};

    stage_tile(X, Wroot, Xs[0], Ws[0], w, stHalf, rsub, srcColB, 0, row0, rowMax);

#pragma unroll
    for (int t = 0; t < 4; ++t) {
        const int cur = t & 1;
        if (t < 3) {
            const unsigned short* Fn = (t + 1 < 2) ? X : AGG;
            const unsigned short* Wn = (t + 1 < 2) ? Wroot : Wrel;
            stage_tile(Fn, Wn, Xs[cur ^ 1], Ws[cur ^ 1],
                       w, stHalf, rsub, srcColB, ((t + 1) & 1) * 64, row0, rowMax);
            asm volatile("s_waitcnt vmcnt(8)" ::: "memory");
        } else {
            asm volatile("s_waitcnt vmcnt(0)" ::: "memory");
        }
        __builtin_amdgcn_s_barrier();

#pragma unroll
        for (int ks = 0; ks < 2; ++ks) {
            bf16x8 af[4], bfr[4];
            const int kB = (ks * 64 + lk * 16) ^ swz;
#pragma unroll
            for (int m = 0; m < 4; ++m) {
                const int row = R0 + m * 16 + lr;
                af[m] = *reinterpret_cast<const bf16x8*>((const char*)Xs[cur] + row * 128 + kB);
            }
#pragma unroll
            for (int n = 0; n < 4; ++n) {
                const int col = C0 + n * 16 + lr;
                bfr[n] = *reinterpret_cast<const bf16x8*>((const char*)Ws[cur] + col * 128 + kB);
            }
#pragma unroll
            for (int m = 0; m < 4; ++m)
#pragma unroll
                for (int n = 0; n < 4; ++n)
                    acc[m][n] = __builtin_amdgcn_mfma_f32_16x16x32_bf16(
                        af[m], bfr[n], acc[m][n], 0, 0, 0);
        }
        if (t < 3) __builtin_amdgcn_s_barrier();
    }

    float bv[4];
#pragma unroll
    for (int n = 0; n < 4; ++n) bv[n] = bias[C0 + n * 16 + lr];

#pragma unroll
    for (int m = 0; m < 4; ++m) {
        const int rbase = row0 + R0 + m * 16 + lk * 4;
#pragma unroll
        for (int j = 0; j < 4; ++j) {
            const int r = rbase + j;
            if (r < nRows) {
#pragma unroll
                for (int n = 0; n < 4; ++n) {
                    const int col = C0 + n * 16 + lr;
                    float v = acc[m][n][j] + bv[n];
                    if (MODE == 0) {
                        v = fmaxf(v, 0.f);
                        ((unsigned short*)OUTv)[(size_t)r * HID + col] = f2bf(v);
                    } else {
                        ((float*)OUTv)[(size_t)r * HID + col] = v;
                    }
                }
            }
        }
    }
}

// ===========================================================================
extern "C" void kernel_launch(void* const* d_in, const int* in_sizes, int n_in,
                              void* d_out, int out_size, void* d_ws, size_t ws_size,
                              hipStream_t stream)
{
    const float* x      = (const float*)d_in[0];
    const int*   ei     = (const int*)  d_in[1];
    const float* Wrel0  = (const float*)d_in[2];
    const float* b0     = (const float*)d_in[3];
    const float* Wroot0 = (const float*)d_in[4];
    const float* Wrel1  = (const float*)d_in[5];
    const float* b1     = (const float*)d_in[6];
    const float* Wroot1 = (const float*)d_in[7];
    const float* Wrel2  = (const float*)d_in[8];
    const float* b2     = (const float*)d_in[9];
    const float* Wroot2 = (const float*)d_in[10];

    const int nNodes = in_sizes[0] / HID;   // 100000
    const int nEdges = in_sizes[1] / 2;     // 640000
    const int* srcI = ei;
    const int* dstI = ei + nEdges;
    const size_t nF = (size_t)nNodes * HID;

    float* OUT = (float*)d_out;

    // ---- workspace layout
    unsigned short* xb   = (unsigned short*)d_ws;
    unsigned short* hA   = xb + nF;
    unsigned short* hB   = hA + nF;
    unsigned short* aggb = hB + nF;
    unsigned short* wb   = aggb + nF;          // 6 x 128*128 bf16
    int* deg       = (int*)(wb + 6 * HID * HID);
    int* part      = deg + nNodes;
    int* rowStart  = part + nNodes;            // nNodes+1
    int* blockSums = rowStart + nNodes + 1;    // <=128
    int* rank      = blockSums + 128;          // nEdges
    int* eSrc      = rank + nEdges;            // nEdges

    unsigned short* Wrel0b  = wb + 0 * HID * HID;
    unsigned short* Wroot0b = wb + 1 * HID * HID;
    unsigned short* Wrel1b  = wb + 2 * HID * HID;
    unsigned short* Wroot1b = wb + 3 * HID * HID;
    unsigned short* Wrel2b  = wb + 4 * HID * HID;
    unsigned short* Wroot2b = wb + 5 * HID * HID;

    // ---- fused prep: hist_rank ILP (first) | cvt_w | cvt_x
    hipMemsetAsync(deg, 0, (size_t)nNodes * sizeof(int), stream);
    PrepArgs pa;
    pa.dst = dstI; pa.deg = deg; pa.rank = rank; pa.nEdges = nEdges;
    pa.ws[0] = Wrel0;  pa.wd[0] = Wrel0b;
    pa.ws[1] = Wroot0; pa.wd[1] = Wroot0b;
    pa.ws[2] = Wrel1;  pa.wd[2] = Wrel1b;
    pa.ws[3] = Wroot1; pa.wd[3] = Wroot1b;
    pa.ws[4] = Wrel2;  pa.wd[4] = Wrel2b;
    pa.ws[5] = Wroot2; pa.wd[5] = Wroot2b;
    pa.x = x; pa.xb = xb; pa.n4 = (int)(nF / 4);
    pa.histBlocks = (nEdges + 2047) / 2048;                 // 313 (8 edges/thread)
    pa.cvtwBlocks = 96;
    const int prepGrid = pa.histBlocks + pa.cvtwBlocks + (pa.n4 + 255) / 256;
    prep_k<<<prepGrid, 256, 0, stream>>>(pa);

    // ---- CSR: scan1, then fused [scan2+scan3 | fill]
    const int nb = (nNodes + 1023) / 1024;                  // 98
    scan1_k<<<nb, 256, 0, stream>>>(deg, part, blockSums, nNodes);
    const int nodeBlocks = (nNodes + 256) / 256;            // covers i==n too
    const int edgeBlocks = (nEdges + 255) / 256;
    scanfill_k<<<nodeBlocks + edgeBlocks, 256, 0, stream>>>(
        part, blockSums, nb, rowStart, srcI, dstI, rank, eSrc,
        nNodes, nEdges, nodeBlocks);

    const int aGrid = (int)(((size_t)(nNodes + 3) / 4 * 64 + 255) / 256);  // 4 nodes/wave
    const int gGrid = (nNodes + 127) / 128;

    // ---- layer 0
    gather_agg_k<<<aGrid, 256, 0, stream>>>(xb, rowStart, eSrc, aggb, nNodes);
    gemm_mfma_k<0><<<gGrid, 256, 0, stream>>>(xb, aggb, Wroot0b, Wrel0b, b0, hA, nNodes);

    // ---- layer 1
    gather_agg_k<<<aGrid, 256, 0, stream>>>(hA, rowStart, eSrc, aggb, nNodes);
    gemm_mfma_k<0><<<gGrid, 256, 0, stream>>>(hA, aggb, Wroot1b, Wrel1b, b1, hB, nNodes);

    // ---- layer 2 (f32 out, no ReLU)
    gather_agg_k<<<aGrid, 256, 0, stream>>>(hB, rowStart, eSrc, aggb, nNodes);
    gemm_mfma_k<1><<<gGrid, 256, 0, stream>>>(hB, aggb, Wroot2b, Wrel2b, b2, OUT, nNodes);
}

// Round 13
// 201.066 us; speedup vs baseline: 1.0396x; 1.0018x over previous
//
#include <hip/hip_runtime.h>

constexpr int HID = 128;

typedef __attribute__((ext_vector_type(8))) short bf16x8;
typedef __attribute__((ext_vector_type(4))) float f32x4;

__device__ __forceinline__ unsigned short f2bf(float f) {
    unsigned int u = __float_as_uint(f);
    u += 0x7fffu + ((u >> 16) & 1u);            // RNE
    return (unsigned short)(u >> 16);
}
__device__ __forceinline__ float bf_lo(unsigned int v) { return __uint_as_float(v << 16); }
__device__ __forceinline__ float bf_hi(unsigned int v) { return __uint_as_float(v & 0xffff0000u); }

__device__ __forceinline__ void gload16(const void* g, void* l) {
    __builtin_amdgcn_global_load_lds(
        (const __attribute__((address_space(1))) void*)g,
        (__attribute__((address_space(3))) void*)l, 16, 0, 0);
}

// ===========================================================================
// prep_k: fused [hist_rank (8-edge ILP) | cvt_w | cvt_x]  (proven R11)
// ===========================================================================
struct PrepArgs {
    const int* dst; int* deg; int* rank; int nEdges;          // hist_rank
    const float* ws[6]; unsigned short* wd[6];                // cvt_w
    const float* x; unsigned short* xb; int n4;               // cvt_x
    int histBlocks, cvtwBlocks;                               // partition
};

__global__ __launch_bounds__(256) void prep_k(PrepArgs a)
{
    const int b   = blockIdx.x;
    const int tid = threadIdx.x;
    if (b < a.histBlocks) {
        const int i0 = (b * 256 + tid) * 8;
        if (i0 + 8 <= a.nEdges) {
            const int4 d0 = *reinterpret_cast<const int4*>(a.dst + i0);
            const int4 d1 = *reinterpret_cast<const int4*>(a.dst + i0 + 4);
            int4 r0, r1;
            r0.x = atomicAdd(&a.deg[d0.x], 1);
            r0.y = atomicAdd(&a.deg[d0.y], 1);
            r0.z = atomicAdd(&a.deg[d0.z], 1);
            r0.w = atomicAdd(&a.deg[d0.w], 1);
            r1.x = atomicAdd(&a.deg[d1.x], 1);
            r1.y = atomicAdd(&a.deg[d1.y], 1);
            r1.z = atomicAdd(&a.deg[d1.z], 1);
            r1.w = atomicAdd(&a.deg[d1.w], 1);
            *reinterpret_cast<int4*>(a.rank + i0)     = r0;
            *reinterpret_cast<int4*>(a.rank + i0 + 4) = r1;
        } else {
            for (int i = i0; i < a.nEdges; ++i)
                a.rank[i] = atomicAdd(&a.deg[a.dst[i]], 1);
        }
    } else if (b < a.histBlocks + a.cvtwBlocks) {
        const int idx   = b - a.histBlocks;
        const int which = idx >> 4;                 // 6 weights x 16 blocks
        const int i     = (idx & 15) * 256 + tid;   // < 4096
        const float4 v = reinterpret_cast<const float4*>(a.ws[which])[i];
        ushort4 o;
        o.x = f2bf(v.x); o.y = f2bf(v.y); o.z = f2bf(v.z); o.w = f2bf(v.w);
        reinterpret_cast<ushort4*>(a.wd[which])[i] = o;
    } else {
        const int i = (b - a.histBlocks - a.cvtwBlocks) * 256 + tid;
        if (i >= a.n4) return;
        const float4 v = reinterpret_cast<const float4*>(a.x)[i];
        ushort4 o;
        o.x = f2bf(v.x); o.y = f2bf(v.y); o.z = f2bf(v.z); o.w = f2bf(v.w);
        reinterpret_cast<ushort4*>(a.xb)[i] = o;
    }
}

// ===========================================================================
// scan1: per-block (1024 nodes) exclusive scan -> part + blockSums
// ===========================================================================
__global__ __launch_bounds__(256) void scan1_k(
    const int* __restrict__ deg, int* __restrict__ part,
    int* __restrict__ blockSums, int n)
{
    __shared__ int s[256];
    const int t = threadIdx.x;
    const int i = blockIdx.x * 1024 + t * 4;
    const int e0 = (i + 0 < n) ? deg[i + 0] : 0;
    const int e1 = (i + 1 < n) ? deg[i + 1] : 0;
    const int e2 = (i + 2 < n) ? deg[i + 2] : 0;
    const int e3 = (i + 3 < n) ? deg[i + 3] : 0;
    const int local = e0 + e1 + e2 + e3;
    s[t] = local;
    __syncthreads();
    for (int off = 1; off < 256; off <<= 1) {
        int v = 0;
        if (t >= off) v = s[t - off];
        __syncthreads();
        if (t >= off) s[t] += v;
        __syncthreads();
    }
    const int incl = s[t];
    int excl = incl - local;
    if (t == 255) blockSums[blockIdx.x] = incl;
    if (i + 0 < n) part[i + 0] = excl; excl += e0;
    if (i + 1 < n) part[i + 1] = excl; excl += e1;
    if (i + 2 < n) part[i + 2] = excl; excl += e2;
    if (i + 3 < n) part[i + 3] = excl;
}

// ===========================================================================
// scanfill_k: fused [scan2 (redundant per-block) + scan3 | fill2].
// Every block redundantly exclusive-scans blockSums (<=128 ints, ~us-scale
// free) in LDS, eliminating the cross-kernel dependency; then node-domain
// blocks write rowStart, edge-domain blocks scatter eSrc.
// ===========================================================================
__global__ __launch_bounds__(256) void scanfill_k(
    const int* __restrict__ part, const int* __restrict__ blockSums, int nb,
    int* __restrict__ rowStart,
    const int* __restrict__ src, const int* __restrict__ dst,
    const int* __restrict__ rank, int* __restrict__ eSrc,
    int n, int nEdges, int nodeBlocks)
{
    __shared__ int bs[128];
    const int t = threadIdx.x;
    // redundant exclusive scan of blockSums in every block
    if (t < 128) {
        const int v = (t < nb) ? blockSums[t] : 0;
        bs[t] = v;
    }
    __syncthreads();
    for (int off = 1; off < 128; off <<= 1) {
        int u = 0;
        if (t >= off && t < 128) u = bs[t - off];
        __syncthreads();
        if (t >= off && t < 128) bs[t] += u;
        __syncthreads();
    }
    // bs now inclusive; convert on use: excl(k) = bs[k] - orig. Simpler:
    // store exclusive via second pass
    __shared__ int bse[128];
    if (t < 128) {
        const int v = (t < nb) ? blockSums[t] : 0;
        bse[t] = bs[t] - v;
    }
    __syncthreads();

    if (blockIdx.x < (unsigned)nodeBlocks) {
        const int i = blockIdx.x * 256 + t;
        if (i < n) rowStart[i] = part[i] + bse[i >> 10];
        if (i == n) rowStart[n] = nEdges;
    } else {
        const int i = (blockIdx.x - nodeBlocks) * 256 + t;
        if (i < nEdges) {
            const int d = dst[i];
            eSrc[part[d] + bse[d >> 10] + rank[i]] = src[i];
        }
    }
}

// ===========================================================================
// Gather aggregation (bf16): 4 nodes/wave, 16 lanes/node, uint4/lane,
// batched ILP 8/4/2/1. (proven R7/R9 config)
// ===========================================================================
__global__ __launch_bounds__(256) void gather_agg_k(
    const unsigned short* __restrict__ feat,
    const int*            __restrict__ rowStart,
    const int*            __restrict__ eSrc,
    unsigned short*       __restrict__ agg,
    int nNodes)
{
    const int wid  = (blockIdx.x * blockDim.x + threadIdx.x) >> 6;
    const int lane = threadIdx.x & 63;
    const int g    = lane >> 4;
    const int sl   = lane & 15;
    const int node = wid * 4 + g;
    if (node >= nNodes) return;

    const int beg = rowStart[node];
    const int end = rowStart[node + 1];
    const size_t colOff = (size_t)sl * 8;
    const int gbase = g << 4;

    float acc[8];
#pragma unroll
    for (int q = 0; q < 8; ++q) acc[q] = 0.f;

    for (int base = beg; base < end; base += 16) {
        const int cnt = min(16, end - base);
        const int si = eSrc[base + min(sl, cnt - 1)];

        int j = 0;
        for (; j + 8 <= cnt; j += 8) {
            uint4 v[8];
#pragma unroll
            for (int q = 0; q < 8; ++q) {
                const int s = __shfl(si, gbase + j + q, 64);
                v[q] = *reinterpret_cast<const uint4*>(feat + (size_t)s * HID + colOff);
            }
#pragma unroll
            for (int q = 0; q < 8; ++q) {
                acc[0] += bf_lo(v[q].x); acc[1] += bf_hi(v[q].x);
                acc[2] += bf_lo(v[q].y); acc[3] += bf_hi(v[q].y);
                acc[4] += bf_lo(v[q].z); acc[5] += bf_hi(v[q].z);
                acc[6] += bf_lo(v[q].w); acc[7] += bf_hi(v[q].w);
            }
        }
        if (j + 4 <= cnt) {
            uint4 v[4];
#pragma unroll
            for (int q = 0; q < 4; ++q) {
                const int s = __shfl(si, gbase + j + q, 64);
                v[q] = *reinterpret_cast<const uint4*>(feat + (size_t)s * HID + colOff);
            }
#pragma unroll
            for (int q = 0; q < 4; ++q) {
                acc[0] += bf_lo(v[q].x); acc[1] += bf_hi(v[q].x);
                acc[2] += bf_lo(v[q].y); acc[3] += bf_hi(v[q].y);
                acc[4] += bf_lo(v[q].z); acc[5] += bf_hi(v[q].z);
                acc[6] += bf_lo(v[q].w); acc[7] += bf_hi(v[q].w);
            }
            j += 4;
        }
        if (j + 2 <= cnt) {
            uint4 v[2];
#pragma unroll
            for (int q = 0; q < 2; ++q) {
                const int s = __shfl(si, gbase + j + q, 64);
                v[q] = *reinterpret_cast<const uint4*>(feat + (size_t)s * HID + colOff);
            }
#pragma unroll
            for (int q = 0; q < 2; ++q) {
                acc[0] += bf_lo(v[q].x); acc[1] += bf_hi(v[q].x);
                acc[2] += bf_lo(v[q].y); acc[3] += bf_hi(v[q].y);
                acc[4] += bf_lo(v[q].z); acc[5] += bf_hi(v[q].z);
                acc[6] += bf_lo(v[q].w); acc[7] += bf_hi(v[q].w);
            }
            j += 2;
        }
        if (j < cnt) {
            const int s = __shfl(si, gbase + j, 64);
            const uint4 v = *reinterpret_cast<const uint4*>(feat + (size_t)s * HID + colOff);
            acc[0] += bf_lo(v.x); acc[1] += bf_hi(v.x);
            acc[2] += bf_lo(v.y); acc[3] += bf_hi(v.y);
            acc[4] += bf_lo(v.z); acc[5] += bf_hi(v.z);
            acc[6] += bf_lo(v.w); acc[7] += bf_hi(v.w);
        }
    }

    uint4 o;
    o.x = (unsigned int)f2bf(acc[0]) | ((unsigned int)f2bf(acc[1]) << 16);
    o.y = (unsigned int)f2bf(acc[2]) | ((unsigned int)f2bf(acc[3]) << 16);
    o.z = (unsigned int)f2bf(acc[4]) | ((unsigned int)f2bf(acc[5]) << 16);
    o.w = (unsigned int)f2bf(acc[6]) | ((unsigned int)f2bf(acc[7]) << 16);
    *reinterpret_cast<uint4*>(agg + (size_t)node * HID + colOff) = o;
}

// ===========================================================================
// bf16 MFMA dual-GEMM, 2-phase double-buffered pipeline (proven R9 config).
// ===========================================================================
__device__ __forceinline__ void stage_tile(
    const unsigned short* __restrict__ F, const unsigned short* __restrict__ Wm,
    unsigned short* XsBuf, unsigned short* WsBuf,
    int w, int stHalf, int rsub, int srcColB, int k0, int row0, int rowMax)
{
    if (w < 2) {
#pragma unroll
        for (int q = 0; q < 8; ++q) {
            const int row = stHalf * 64 + q * 8 + rsub;
            const int gr  = min(row0 + row, rowMax);
            gload16((const char*)(F + (size_t)gr * HID + k0) + srcColB,
                    XsBuf + (stHalf * 64 + q * 8) * 64);
        }
    } else {
#pragma unroll
        for (int q = 0; q < 8; ++q) {
            const int row = stHalf * 64 + q * 8 + rsub;
            gload16((const char*)(Wm + (size_t)row * HID + k0) + srcColB,
                    WsBuf + (stHalf * 64 + q * 8) * 64);
        }
    }
}

template <int MODE>
__global__ __launch_bounds__(256) void gemm_mfma_k(
    const unsigned short* __restrict__ X,
    const unsigned short* __restrict__ AGG,
    const unsigned short* __restrict__ Wroot,
    const unsigned short* __restrict__ Wrel,
    const float*          __restrict__ bias,
    void*                 __restrict__ OUTv,
    int nRows)
{
    __shared__ unsigned short Xs[2][128 * 64];
    __shared__ unsigned short Ws[2][128 * 64];

    const int tid  = threadIdx.x;
    const int lane = tid & 63;
    const int w    = tid >> 6;
    const int row0 = blockIdx.x * 128;

    const int wr = w >> 1, wc = w & 1;
    const int R0 = wr * 64, C0 = wc * 64;
    const int lr = lane & 15, lk = lane >> 4;
    const int swz = (lr & 7) << 4;

    const int rsub    = lane >> 3;
    const int srcColB = (((lane & 7) ^ rsub) << 4);
    const int stHalf  = w & 1;
    const int rowMax  = nRows - 1;

    f32x4 acc[4][4];
#pragma unroll
    for (int m = 0; m < 4; ++m)
#pragma unroll
        for (int n = 0; n < 4; ++n) acc[m][n] = f32x4{0.f, 0.f, 0.f, 0.f};

    stage_tile(X, Wroot, Xs[0], Ws[0], w, stHalf, rsub, srcColB, 0, row0, rowMax);

#pragma unroll
    for (int t = 0; t < 4; ++t) {
        const int cur = t & 1;
        if (t < 3) {
            const unsigned short* Fn = (t + 1 < 2) ? X : AGG;
            const unsigned short* Wn = (t + 1 < 2) ? Wroot : Wrel;
            stage_tile(Fn, Wn, Xs[cur ^ 1], Ws[cur ^ 1],
                       w, stHalf, rsub, srcColB, ((t + 1) & 1) * 64, row0, rowMax);
            asm volatile("s_waitcnt vmcnt(8)" ::: "memory");
        } else {
            asm volatile("s_waitcnt vmcnt(0)" ::: "memory");
        }
        __builtin_amdgcn_s_barrier();

#pragma unroll
        for (int ks = 0; ks < 2; ++ks) {
            bf16x8 af[4], bfr[4];
            const int kB = (ks * 64 + lk * 16) ^ swz;
#pragma unroll
            for (int m = 0; m < 4; ++m) {
                const int row = R0 + m * 16 + lr;
                af[m] = *reinterpret_cast<const bf16x8*>((const char*)Xs[cur] + row * 128 + kB);
            }
#pragma unroll
            for (int n = 0; n < 4; ++n) {
                const int col = C0 + n * 16 + lr;
                bfr[n] = *reinterpret_cast<const bf16x8*>((const char*)Ws[cur] + col * 128 + kB);
            }
#pragma unroll
            for (int m = 0; m < 4; ++m)
#pragma unroll
                for (int n = 0; n < 4; ++n)
                    acc[m][n] = __builtin_amdgcn_mfma_f32_16x16x32_bf16(
                        af[m], bfr[n], acc[m][n], 0, 0, 0);
        }
        if (t < 3) __builtin_amdgcn_s_barrier();
    }

    float bv[4];
#pragma unroll
    for (int n = 0; n < 4; ++n) bv[n] = bias[C0 + n * 16 + lr];

#pragma unroll
    for (int m = 0; m < 4; ++m) {
        const int rbase = row0 + R0 + m * 16 + lk * 4;
#pragma unroll
        for (int j = 0; j < 4; ++j) {
            const int r = rbase + j;
            if (r < nRows) {
#pragma unroll
                for (int n = 0; n < 4; ++n) {
                    const int col = C0 + n * 16 + lr;
                    float v = acc[m][n][j] + bv[n];
                    if (MODE == 0) {
                        v = fmaxf(v, 0.f);
                        ((unsigned short*)OUTv)[(size_t)r * HID + col] = f2bf(v);
                    } else {
                        ((float*)OUTv)[(size_t)r * HID + col] = v;
                    }
                }
            }
        }
    }
}

// ===========================================================================
extern "C" void kernel_launch(void* const* d_in, const int* in_sizes, int n_in,
                              void* d_out, int out_size, void* d_ws, size_t ws_size,
                              hipStream_t stream)
{
    const float* x      = (const float*)d_in[0];
    const int*   ei     = (const int*)  d_in[1];
    const float* Wrel0  = (const float*)d_in[2];
    const float* b0     = (const float*)d_in[3];
    const float* Wroot0 = (const float*)d_in[4];
    const float* Wrel1  = (const float*)d_in[5];
    const float* b1     = (const float*)d_in[6];
    const float* Wroot1 = (const float*)d_in[7];
    const float* Wrel2  = (const float*)d_in[8];
    const float* b2     = (const float*)d_in[9];
    const float* Wroot2 = (const float*)d_in[10];

    const int nNodes = in_sizes[0] / HID;   // 100000
    const int nEdges = in_sizes[1] / 2;     // 640000
    const int* srcI = ei;
    const int* dstI = ei + nEdges;
    const size_t nF = (size_t)nNodes * HID;

    float* OUT = (float*)d_out;

    // ---- workspace layout
    unsigned short* xb   = (unsigned short*)d_ws;
    unsigned short* hA   = xb + nF;
    unsigned short* hB   = hA + nF;
    unsigned short* aggb = hB + nF;
    unsigned short* wb   = aggb + nF;          // 6 x 128*128 bf16
    int* deg       = (int*)(wb + 6 * HID * HID);
    int* part      = deg + nNodes;
    int* rowStart  = part + nNodes;            // nNodes+1
    int* blockSums = rowStart + nNodes + 1;    // <=128
    int* rank      = blockSums + 128;          // nEdges
    int* eSrc      = rank + nEdges;            // nEdges

    unsigned short* Wrel0b  = wb + 0 * HID * HID;
    unsigned short* Wroot0b = wb + 1 * HID * HID;
    unsigned short* Wrel1b  = wb + 2 * HID * HID;
    unsigned short* Wroot1b = wb + 3 * HID * HID;
    unsigned short* Wrel2b  = wb + 4 * HID * HID;
    unsigned short* Wroot2b = wb + 5 * HID * HID;

    // ---- fused prep: hist_rank ILP (first) | cvt_w | cvt_x
    hipMemsetAsync(deg, 0, (size_t)nNodes * sizeof(int), stream);
    PrepArgs pa;
    pa.dst = dstI; pa.deg = deg; pa.rank = rank; pa.nEdges = nEdges;
    pa.ws[0] = Wrel0;  pa.wd[0] = Wrel0b;
    pa.ws[1] = Wroot0; pa.wd[1] = Wroot0b;
    pa.ws[2] = Wrel1;  pa.wd[2] = Wrel1b;
    pa.ws[3] = Wroot1; pa.wd[3] = Wroot1b;
    pa.ws[4] = Wrel2;  pa.wd[4] = Wrel2b;
    pa.ws[5] = Wroot2; pa.wd[5] = Wroot2b;
    pa.x = x; pa.xb = xb; pa.n4 = (int)(nF / 4);
    pa.histBlocks = (nEdges + 2047) / 2048;                 // 313 (8 edges/thread)
    pa.cvtwBlocks = 96;
    const int prepGrid = pa.histBlocks + pa.cvtwBlocks + (pa.n4 + 255) / 256;
    prep_k<<<prepGrid, 256, 0, stream>>>(pa);

    // ---- CSR: scan1, then fused [scan2+scan3 | fill]
    const int nb = (nNodes + 1023) / 1024;                  // 98
    scan1_k<<<nb, 256, 0, stream>>>(deg, part, blockSums, nNodes);
    const int nodeBlocks = (nNodes + 256) / 256;            // covers i==n too
    const int edgeBlocks = (nEdges + 255) / 256;
    scanfill_k<<<nodeBlocks + edgeBlocks, 256, 0, stream>>>(
        part, blockSums, nb, rowStart, srcI, dstI, rank, eSrc,
        nNodes, nEdges, nodeBlocks);

    const int aGrid = (int)(((size_t)(nNodes + 3) / 4 * 64 + 255) / 256);  // 4 nodes/wave
    const int gGrid = (nNodes + 127) / 128;

    // ---- layer 0
    gather_agg_k<<<aGrid, 256, 0, stream>>>(xb, rowStart, eSrc, aggb, nNodes);
    gemm_mfma_k<0><<<gGrid, 256, 0, stream>>>(xb, aggb, Wroot0b, Wrel0b, b0, hA, nNodes);

    // ---- layer 1
    gather_agg_k<<<aGrid, 256, 0, stream>>>(hA, rowStart, eSrc, aggb, nNodes);
    gemm_mfma_k<0><<<gGrid, 256, 0, stream>>>(hA, aggb, Wroot1b, Wrel1b, b1, hB, nNodes);

    // ---- layer 2 (f32 out, no ReLU)
    gather_agg_k<<<aGrid, 256, 0, stream>>>(hB, rowStart, eSrc, aggb, nNodes);
    gemm_mfma_k<1><<<gGrid, 256, 0, stream>>>(hB, aggb, Wroot2b, Wrel2b, b2, OUT, nNodes);
}

// Round 14
// 200.230 us; speedup vs baseline: 1.0439x; 1.0042x over previous
//
#include <hip/hip_runtime.h>

constexpr int HID = 128;

typedef __attribute__((ext_vector_type(8))) short bf16x8;
typedef __attribute__((ext_vector_type(4))) float f32x4;

__device__ __forceinline__ unsigned short f2bf(float f) {
    unsigned int u = __float_as_uint(f);
    u += 0x7fffu + ((u >> 16) & 1u);            // RNE
    return (unsigned short)(u >> 16);
}
__device__ __forceinline__ float bf_lo(unsigned int v) { return __uint_as_float(v << 16); }
__device__ __forceinline__ float bf_hi(unsigned int v) { return __uint_as_float(v & 0xffff0000u); }

__device__ __forceinline__ void gload16(const void* g, void* l) {
    __builtin_amdgcn_global_load_lds(
        (const __attribute__((address_space(1))) void*)g,
        (__attribute__((address_space(3))) void*)l, 16, 0, 0);
}

// ===========================================================================
// zero_deg_k: replaces hipMemsetAsync(deg, 400KB) whose rocclr fill showed
// 40us in-profile. 25000 int4 stores, 98 blocks -> ~1-2us of real work.
// ===========================================================================
__global__ __launch_bounds__(256) void zero_deg_k(int4* __restrict__ deg4, int n4)
{
    const int i = blockIdx.x * 256 + threadIdx.x;
    if (i < n4) deg4[i] = make_int4(0, 0, 0, 0);
}

// ===========================================================================
// prep_k: fused [hist_rank (8-edge ILP) | cvt_w | cvt_x]  (proven R11)
// ===========================================================================
struct PrepArgs {
    const int* dst; int* deg; int* rank; int nEdges;          // hist_rank
    const float* ws[6]; unsigned short* wd[6];                // cvt_w
    const float* x; unsigned short* xb; int n4;               // cvt_x
    int histBlocks, cvtwBlocks;                               // partition
};

__global__ __launch_bounds__(256) void prep_k(PrepArgs a)
{
    const int b   = blockIdx.x;
    const int tid = threadIdx.x;
    if (b < a.histBlocks) {
        const int i0 = (b * 256 + tid) * 8;
        if (i0 + 8 <= a.nEdges) {
            const int4 d0 = *reinterpret_cast<const int4*>(a.dst + i0);
            const int4 d1 = *reinterpret_cast<const int4*>(a.dst + i0 + 4);
            int4 r0, r1;
            r0.x = atomicAdd(&a.deg[d0.x], 1);
            r0.y = atomicAdd(&a.deg[d0.y], 1);
            r0.z = atomicAdd(&a.deg[d0.z], 1);
            r0.w = atomicAdd(&a.deg[d0.w], 1);
            r1.x = atomicAdd(&a.deg[d1.x], 1);
            r1.y = atomicAdd(&a.deg[d1.y], 1);
            r1.z = atomicAdd(&a.deg[d1.z], 1);
            r1.w = atomicAdd(&a.deg[d1.w], 1);
            *reinterpret_cast<int4*>(a.rank + i0)     = r0;
            *reinterpret_cast<int4*>(a.rank + i0 + 4) = r1;
        } else {
            for (int i = i0; i < a.nEdges; ++i)
                a.rank[i] = atomicAdd(&a.deg[a.dst[i]], 1);
        }
    } else if (b < a.histBlocks + a.cvtwBlocks) {
        const int idx   = b - a.histBlocks;
        const int which = idx >> 4;                 // 6 weights x 16 blocks
        const int i     = (idx & 15) * 256 + tid;   // < 4096
        const float4 v = reinterpret_cast<const float4*>(a.ws[which])[i];
        ushort4 o;
        o.x = f2bf(v.x); o.y = f2bf(v.y); o.z = f2bf(v.z); o.w = f2bf(v.w);
        reinterpret_cast<ushort4*>(a.wd[which])[i] = o;
    } else {
        const int i = (b - a.histBlocks - a.cvtwBlocks) * 256 + tid;
        if (i >= a.n4) return;
        const float4 v = reinterpret_cast<const float4*>(a.x)[i];
        ushort4 o;
        o.x = f2bf(v.x); o.y = f2bf(v.y); o.z = f2bf(v.z); o.w = f2bf(v.w);
        reinterpret_cast<ushort4*>(a.xb)[i] = o;
    }
}

// ===========================================================================
// scan1: per-block (1024 nodes) exclusive scan -> part + blockSums
// ===========================================================================
__global__ __launch_bounds__(256) void scan1_k(
    const int* __restrict__ deg, int* __restrict__ part,
    int* __restrict__ blockSums, int n)
{
    __shared__ int s[256];
    const int t = threadIdx.x;
    const int i = blockIdx.x * 1024 + t * 4;
    const int e0 = (i + 0 < n) ? deg[i + 0] : 0;
    const int e1 = (i + 1 < n) ? deg[i + 1] : 0;
    const int e2 = (i + 2 < n) ? deg[i + 2] : 0;
    const int e3 = (i + 3 < n) ? deg[i + 3] : 0;
    const int local = e0 + e1 + e2 + e3;
    s[t] = local;
    __syncthreads();
    for (int off = 1; off < 256; off <<= 1) {
        int v = 0;
        if (t >= off) v = s[t - off];
        __syncthreads();
        if (t >= off) s[t] += v;
        __syncthreads();
    }
    const int incl = s[t];
    int excl = incl - local;
    if (t == 255) blockSums[blockIdx.x] = incl;
    if (i + 0 < n) part[i + 0] = excl; excl += e0;
    if (i + 1 < n) part[i + 1] = excl; excl += e1;
    if (i + 2 < n) part[i + 2] = excl; excl += e2;
    if (i + 3 < n) part[i + 3] = excl;
}

// ===========================================================================
// scanfill_k: fused [scan2 (redundant per-block) + scan3 | fill2]  (R13)
// ===========================================================================
__global__ __launch_bounds__(256) void scanfill_k(
    const int* __restrict__ part, const int* __restrict__ blockSums, int nb,
    int* __restrict__ rowStart,
    const int* __restrict__ src, const int* __restrict__ dst,
    const int* __restrict__ rank, int* __restrict__ eSrc,
    int n, int nEdges, int nodeBlocks)
{
    __shared__ int bs[128];
    const int t = threadIdx.x;
    if (t < 128) {
        const int v = (t < nb) ? blockSums[t] : 0;
        bs[t] = v;
    }
    __syncthreads();
    for (int off = 1; off < 128; off <<= 1) {
        int u = 0;
        if (t >= off && t < 128) u = bs[t - off];
        __syncthreads();
        if (t >= off && t < 128) bs[t] += u;
        __syncthreads();
    }
    __shared__ int bse[128];
    if (t < 128) {
        const int v = (t < nb) ? blockSums[t] : 0;
        bse[t] = bs[t] - v;
    }
    __syncthreads();

    if (blockIdx.x < (unsigned)nodeBlocks) {
        const int i = blockIdx.x * 256 + t;
        if (i < n) rowStart[i] = part[i] + bse[i >> 10];
        if (i == n) rowStart[n] = nEdges;
    } else {
        const int i = (blockIdx.x - nodeBlocks) * 256 + t;
        if (i < nEdges) {
            const int d = dst[i];
            eSrc[part[d] + bse[d >> 10] + rank[i]] = src[i];
        }
    }
}

// ===========================================================================
// Gather aggregation (bf16): 4 nodes/wave, 16 lanes/node, uint4/lane,
// batched ILP 8/4/2/1. At L3-BW floor (~16us) per R13 analysis.
// ===========================================================================
__global__ __launch_bounds__(256) void gather_agg_k(
    const unsigned short* __restrict__ feat,
    const int*            __restrict__ rowStart,
    const int*            __restrict__ eSrc,
    unsigned short*       __restrict__ agg,
    int nNodes)
{
    const int wid  = (blockIdx.x * blockDim.x + threadIdx.x) >> 6;
    const int lane = threadIdx.x & 63;
    const int g    = lane >> 4;
    const int sl   = lane & 15;
    const int node = wid * 4 + g;
    if (node >= nNodes) return;

    const int beg = rowStart[node];
    const int end = rowStart[node + 1];
    const size_t colOff = (size_t)sl * 8;
    const int gbase = g << 4;

    float acc[8];
#pragma unroll
    for (int q = 0; q < 8; ++q) acc[q] = 0.f;

    for (int base = beg; base < end; base += 16) {
        const int cnt = min(16, end - base);
        const int si = eSrc[base + min(sl, cnt - 1)];

        int j = 0;
        for (; j + 8 <= cnt; j += 8) {
            uint4 v[8];
#pragma unroll
            for (int q = 0; q < 8; ++q) {
                const int s = __shfl(si, gbase + j + q, 64);
                v[q] = *reinterpret_cast<const uint4*>(feat + (size_t)s * HID + colOff);
            }
#pragma unroll
            for (int q = 0; q < 8; ++q) {
                acc[0] += bf_lo(v[q].x); acc[1] += bf_hi(v[q].x);
                acc[2] += bf_lo(v[q].y); acc[3] += bf_hi(v[q].y);
                acc[4] += bf_lo(v[q].z); acc[5] += bf_hi(v[q].z);
                acc[6] += bf_lo(v[q].w); acc[7] += bf_hi(v[q].w);
            }
        }
        if (j + 4 <= cnt) {
            uint4 v[4];
#pragma unroll
            for (int q = 0; q < 4; ++q) {
                const int s = __shfl(si, gbase + j + q, 64);
                v[q] = *reinterpret_cast<const uint4*>(feat + (size_t)s * HID + colOff);
            }
#pragma unroll
            for (int q = 0; q < 4; ++q) {
                acc[0] += bf_lo(v[q].x); acc[1] += bf_hi(v[q].x);
                acc[2] += bf_lo(v[q].y); acc[3] += bf_hi(v[q].y);
                acc[4] += bf_lo(v[q].z); acc[5] += bf_hi(v[q].z);
                acc[6] += bf_lo(v[q].w); acc[7] += bf_hi(v[q].w);
            }
            j += 4;
        }
        if (j + 2 <= cnt) {
            uint4 v[2];
#pragma unroll
            for (int q = 0; q < 2; ++q) {
                const int s = __shfl(si, gbase + j + q, 64);
                v[q] = *reinterpret_cast<const uint4*>(feat + (size_t)s * HID + colOff);
            }
#pragma unroll
            for (int q = 0; q < 2; ++q) {
                acc[0] += bf_lo(v[q].x); acc[1] += bf_hi(v[q].x);
                acc[2] += bf_lo(v[q].y); acc[3] += bf_hi(v[q].y);
                acc[4] += bf_lo(v[q].z); acc[5] += bf_hi(v[q].z);
                acc[6] += bf_lo(v[q].w); acc[7] += bf_hi(v[q].w);
            }
            j += 2;
        }
        if (j < cnt) {
            const int s = __shfl(si, gbase + j, 64);
            const uint4 v = *reinterpret_cast<const uint4*>(feat + (size_t)s * HID + colOff);
            acc[0] += bf_lo(v.x); acc[1] += bf_hi(v.x);
            acc[2] += bf_lo(v.y); acc[3] += bf_hi(v.y);
            acc[4] += bf_lo(v.z); acc[5] += bf_hi(v.z);
            acc[6] += bf_lo(v.w); acc[7] += bf_hi(v.w);
        }
    }

    uint4 o;
    o.x = (unsigned int)f2bf(acc[0]) | ((unsigned int)f2bf(acc[1]) << 16);
    o.y = (unsigned int)f2bf(acc[2]) | ((unsigned int)f2bf(acc[3]) << 16);
    o.z = (unsigned int)f2bf(acc[4]) | ((unsigned int)f2bf(acc[5]) << 16);
    o.w = (unsigned int)f2bf(acc[6]) | ((unsigned int)f2bf(acc[7]) << 16);
    *reinterpret_cast<uint4*>(agg + (size_t)node * HID + colOff) = o;
}

// ===========================================================================
// bf16 MFMA dual-GEMM, 2-phase double-buffered pipeline (proven R9 config).
// ===========================================================================
__device__ __forceinline__ void stage_tile(
    const unsigned short* __restrict__ F, const unsigned short* __restrict__ Wm,
    unsigned short* XsBuf, unsigned short* WsBuf,
    int w, int stHalf, int rsub, int srcColB, int k0, int row0, int rowMax)
{
    if (w < 2) {
#pragma unroll
        for (int q = 0; q < 8; ++q) {
            const int row = stHalf * 64 + q * 8 + rsub;
            const int gr  = min(row0 + row, rowMax);
            gload16((const char*)(F + (size_t)gr * HID + k0) + srcColB,
                    XsBuf + (stHalf * 64 + q * 8) * 64);
        }
    } else {
#pragma unroll
        for (int q = 0; q < 8; ++q) {
            const int row = stHalf * 64 + q * 8 + rsub;
            gload16((const char*)(Wm + (size_t)row * HID + k0) + srcColB,
                    WsBuf + (stHalf * 64 + q * 8) * 64);
        }
    }
}

template <int MODE>
__global__ __launch_bounds__(256) void gemm_mfma_k(
    const unsigned short* __restrict__ X,
    const unsigned short* __restrict__ AGG,
    const unsigned short* __restrict__ Wroot,
    const unsigned short* __restrict__ Wrel,
    const float*          __restrict__ bias,
    void*                 __restrict__ OUTv,
    int nRows)
{
    __shared__ unsigned short Xs[2][128 * 64];
    __shared__ unsigned short Ws[2][128 * 64];

    const int tid  = threadIdx.x;
    const int lane = tid & 63;
    const int w    = tid >> 6;
    const int row0 = blockIdx.x * 128;

    const int wr = w >> 1, wc = w & 1;
    const int R0 = wr * 64, C0 = wc * 64;
    const int lr = lane & 15, lk = lane >> 4;
    const int swz = (lr & 7) << 4;

    const int rsub    = lane >> 3;
    const int srcColB = (((lane & 7) ^ rsub) << 4);
    const int stHalf  = w & 1;
    const int rowMax  = nRows - 1;

    f32x4 acc[4][4];
#pragma unroll
    for (int m = 0; m < 4; ++m)
#pragma unroll
        for (int n = 0; n < 4; ++n) acc[m][n] = f32x4{0.f, 0.f, 0.f, 0.f};

    stage_tile(X, Wroot, Xs[0], Ws[0], w, stHalf, rsub, srcColB, 0, row0, rowMax);

#pragma unroll
    for (int t = 0; t < 4; ++t) {
        const int cur = t & 1;
        if (t < 3) {
            const unsigned short* Fn = (t + 1 < 2) ? X : AGG;
            const unsigned short* Wn = (t + 1 < 2) ? Wroot : Wrel;
            stage_tile(Fn, Wn, Xs[cur ^ 1], Ws[cur ^ 1],
                       w, stHalf, rsub, srcColB, ((t + 1) & 1) * 64, row0, rowMax);
            asm volatile("s_waitcnt vmcnt(8)" ::: "memory");
        } else {
            asm volatile("s_waitcnt vmcnt(0)" ::: "memory");
        }
        __builtin_amdgcn_s_barrier();

#pragma unroll
        for (int ks = 0; ks < 2; ++ks) {
            bf16x8 af[4], bfr[4];
            const int kB = (ks * 64 + lk * 16) ^ swz;
#pragma unroll
            for (int m = 0; m < 4; ++m) {
                const int row = R0 + m * 16 + lr;
                af[m] = *reinterpret_cast<const bf16x8*>((const char*)Xs[cur] + row * 128 + kB);
            }
#pragma unroll
            for (int n = 0; n < 4; ++n) {
                const int col = C0 + n * 16 + lr;
                bfr[n] = *reinterpret_cast<const bf16x8*>((const char*)Ws[cur] + col * 128 + kB);
            }
#pragma unroll
            for (int m = 0; m < 4; ++m)
#pragma unroll
                for (int n = 0; n < 4; ++n)
                    acc[m][n] = __builtin_amdgcn_mfma_f32_16x16x32_bf16(
                        af[m], bfr[n], acc[m][n], 0, 0, 0);
        }
        if (t < 3) __builtin_amdgcn_s_barrier();
    }

    float bv[4];
#pragma unroll
    for (int n = 0; n < 4; ++n) bv[n] = bias[C0 + n * 16 + lr];

#pragma unroll
    for (int m = 0; m < 4; ++m) {
        const int rbase = row0 + R0 + m * 16 + lk * 4;
#pragma unroll
        for (int j = 0; j < 4; ++j) {
            const int r = rbase + j;
            if (r < nRows) {
#pragma unroll
                for (int n = 0; n < 4; ++n) {
                    const int col = C0 + n * 16 + lr;
                    float v = acc[m][n][j] + bv[n];
                    if (MODE == 0) {
                        v = fmaxf(v, 0.f);
                        ((unsigned short*)OUTv)[(size_t)r * HID + col] = f2bf(v);
                    } else {
                        ((float*)OUTv)[(size_t)r * HID + col] = v;
                    }
                }
            }
        }
    }
}

// ===========================================================================
extern "C" void kernel_launch(void* const* d_in, const int* in_sizes, int n_in,
                              void* d_out, int out_size, void* d_ws, size_t ws_size,
                              hipStream_t stream)
{
    const float* x      = (const float*)d_in[0];
    const int*   ei     = (const int*)  d_in[1];
    const float* Wrel0  = (const float*)d_in[2];
    const float* b0     = (const float*)d_in[3];
    const float* Wroot0 = (const float*)d_in[4];
    const float* Wrel1  = (const float*)d_in[5];
    const float* b1     = (const float*)d_in[6];
    const float* Wroot1 = (const float*)d_in[7];
    const float* Wrel2  = (const float*)d_in[8];
    const float* b2     = (const float*)d_in[9];
    const float* Wroot2 = (const float*)d_in[10];

    const int nNodes = in_sizes[0] / HID;   // 100000
    const int nEdges = in_sizes[1] / 2;     // 640000
    const int* srcI = ei;
    const int* dstI = ei + nEdges;
    const size_t nF = (size_t)nNodes * HID;

    float* OUT = (float*)d_out;

    // ---- workspace layout
    unsigned short* xb   = (unsigned short*)d_ws;
    unsigned short* hA   = xb + nF;
    unsigned short* hB   = hA + nF;
    unsigned short* aggb = hB + nF;
    unsigned short* wb   = aggb + nF;          // 6 x 128*128 bf16
    int* deg       = (int*)(wb + 6 * HID * HID);
    int* part      = deg + nNodes;
    int* rowStart  = part + nNodes;            // nNodes+1
    int* blockSums = rowStart + nNodes + 1;    // <=128
    int* rank      = blockSums + 128;          // nEdges
    int* eSrc      = rank + nEdges;            // nEdges

    unsigned short* Wrel0b  = wb + 0 * HID * HID;
    unsigned short* Wroot0b = wb + 1 * HID * HID;
    unsigned short* Wrel1b  = wb + 2 * HID * HID;
    unsigned short* Wroot1b = wb + 3 * HID * HID;
    unsigned short* Wrel2b  = wb + 4 * HID * HID;
    unsigned short* Wroot2b = wb + 5 * HID * HID;

    // ---- zero deg (custom kernel; rocclr fill showed 40us for 400KB)
    const int n4 = nNodes / 4;                 // 25000
    zero_deg_k<<<(n4 + 255) / 256, 256, 0, stream>>>((int4*)deg, n4);

    // ---- fused prep: hist_rank ILP (first) | cvt_w | cvt_x
    PrepArgs pa;
    pa.dst = dstI; pa.deg = deg; pa.rank = rank; pa.nEdges = nEdges;
    pa.ws[0] = Wrel0;  pa.wd[0] = Wrel0b;
    pa.ws[1] = Wroot0; pa.wd[1] = Wroot0b;
    pa.ws[2] = Wrel1;  pa.wd[2] = Wrel1b;
    pa.ws[3] = Wroot1; pa.wd[3] = Wroot1b;
    pa.ws[4] = Wrel2;  pa.wd[4] = Wrel2b;
    pa.ws[5] = Wroot2; pa.wd[5] = Wroot2b;
    pa.x = x; pa.xb = xb; pa.n4 = (int)(nF / 4);
    pa.histBlocks = (nEdges + 2047) / 2048;                 // 313 (8 edges/thread)
    pa.cvtwBlocks = 96;
    const int prepGrid = pa.histBlocks + pa.cvtwBlocks + (pa.n4 + 255) / 256;
    prep_k<<<prepGrid, 256, 0, stream>>>(pa);

    // ---- CSR: scan1, then fused [scan2+scan3 | fill]
    const int nb = (nNodes + 1023) / 1024;                  // 98
    scan1_k<<<nb, 256, 0, stream>>>(deg, part, blockSums, nNodes);
    const int nodeBlocks = (nNodes + 256) / 256;
    const int edgeBlocks = (nEdges + 255) / 256;
    scanfill_k<<<nodeBlocks + edgeBlocks, 256, 0, stream>>>(
        part, blockSums, nb, rowStart, srcI, dstI, rank, eSrc,
        nNodes, nEdges, nodeBlocks);

    const int aGrid = (int)(((size_t)(nNodes + 3) / 4 * 64 + 255) / 256);  // 4 nodes/wave
    const int gGrid = (nNodes + 127) / 128;

    // ---- layer 0
    gather_agg_k<<<aGrid, 256, 0, stream>>>(xb, rowStart, eSrc, aggb, nNodes);
    gemm_mfma_k<0><<<gGrid, 256, 0, stream>>>(xb, aggb, Wroot0b, Wrel0b, b0, hA, nNodes);

    // ---- layer 1
    gather_agg_k<<<aGrid, 256, 0, stream>>>(hA, rowStart, eSrc, aggb, nNodes);
    gemm_mfma_k<0><<<gGrid, 256, 0, stream>>>(hA, aggb, Wroot1b, Wrel1b, b1, hB, nNodes);

    // ---- layer 2 (f32 out, no ReLU)
    gather_agg_k<<<aGrid, 256, 0, stream>>>(hB, rowStart, eSrc, aggb, nNodes);
    gemm_mfma_k<1><<<gGrid, 256, 0, stream>>>(hB, aggb, Wroot2b, Wrel2b, b2, OUT, nNodes);
}